// Round 9
// baseline (377.956 us; speedup 1.0000x reference)
//
#include <hip/hip_runtime.h>
#include <math.h>

// DrugEncoder: 2x TransformerConv (heads=1) + global mean pool.
// N=50000 nodes, E=800000 edges, G=512 graphs, D_IN=64, D_HID=D_EMB=128.
//
// R8: gemm4 re-tiled (wave = 64 rows x 32 cols: 1 B ds_read per 4 MFMA),
//     pool fused into layer-2 edge_agg via pre-divided atomics,
//     cnt_inv folded into finalize_rowptr. edge_agg gather at its floor.

constexpr int D1 = 64;
constexpr int DH = 128;
constexpr int SCHUNK = 1024;
constexpr float QSCALE = 0.08838834764831845f;  // 1/sqrt(128)

typedef __attribute__((ext_vector_type(8))) short short8v;
typedef __attribute__((ext_vector_type(4))) float f32x4;

__device__ inline unsigned short bf16r(float f) {
  unsigned u = __float_as_uint(f);
  return (unsigned short)((u + 0x7fffu + ((u >> 16) & 1u)) >> 16);
}

__device__ inline unsigned pack_bf16_2(float a, float b) {
  return (unsigned)bf16r(a) | ((unsigned)bf16r(b) << 16);
}

// ---------------- CSR build ----------------

__global__ void hist_kernel(const int* __restrict__ dst, int* __restrict__ deg, int E) {
  int e = blockIdx.x * blockDim.x + threadIdx.x;
  if (e < E) atomicAdd(&deg[dst[e]], 1);
}

__global__ void scan_chunks(const int* __restrict__ deg, int* __restrict__ incl,
                            int* __restrict__ sums, int N) {
  __shared__ int lds[256];
  int b = blockIdx.x, tid = threadIdx.x;
  int base = b * SCHUNK + tid * 4;
  int e0 = (base + 0 < N) ? deg[base + 0] : 0;
  int e1 = (base + 1 < N) ? deg[base + 1] : 0;
  int e2 = (base + 2 < N) ? deg[base + 2] : 0;
  int e3 = (base + 3 < N) ? deg[base + 3] : 0;
  int t0 = e0, t1 = t0 + e1, t2 = t1 + e2, t3 = t2 + e3;
  lds[tid] = t3;
  __syncthreads();
  for (int off = 1; off < 256; off <<= 1) {
    int v = (tid >= off) ? lds[tid - off] : 0;
    __syncthreads();
    lds[tid] += v;
    __syncthreads();
  }
  int excl = (tid > 0) ? lds[tid - 1] : 0;
  if (base + 0 < N) incl[base + 0] = t0 + excl;
  if (base + 1 < N) incl[base + 1] = t1 + excl;
  if (base + 2 < N) incl[base + 2] = t2 + excl;
  if (base + 3 < N) incl[base + 3] = t3 + excl;
  if (tid == 255) sums[b] = lds[255];
}

// rowptr[n+1] = incl[n] + sum(sums[0..n/SCHUNK)). Threads < NG also compute
// per-graph 1/count from the sorted batch vector.
__global__ void finalize_rowptr(const int* __restrict__ incl, const int* __restrict__ sums,
                                int* __restrict__ rowptr, int N,
                                const int* __restrict__ batch, float* __restrict__ cnt_inv,
                                int NG) {
  int n = blockIdx.x * blockDim.x + threadIdx.x;
  if (n < N) {
    int ch = n / SCHUNK;
    int off = 0;
    for (int i = 0; i < ch; ++i) off += sums[i];
    rowptr[n + 1] = incl[n] + off;
  }
  if (n == 0) rowptr[0] = 0;
  if (n < NG) {
    int g = n;
    int lo = 0, hi = N;
    while (lo < hi) { int mid = (lo + hi) >> 1; if (batch[mid] < g) lo = mid + 1; else hi = mid; }
    int s0 = lo;
    hi = N;
    while (lo < hi) { int mid = (lo + hi) >> 1; if (batch[mid] <= g) lo = mid + 1; else hi = mid; }
    cnt_inv[g] = 1.f / fmaxf((float)(lo - s0), 1.f);
  }
}

__global__ void fill_csr(const int* __restrict__ src, const int* __restrict__ dst,
                         const int* __restrict__ rowptr, int* __restrict__ fill,
                         int* __restrict__ csr_src, int E) {
  int e = blockIdx.x * blockDim.x + threadIdx.x;
  if (e < E) {
    int d = dst[e];
    int pos = rowptr[d] + atomicAdd(&fill[d], 1);
    csr_src[pos] = src[e];
  }
}

// ---------------- prep: W -> transposed bf16 (y<8), x -> bf16 (y==8) ----------------

__global__ void prep_w(const float* w0, const float* w1, const float* w2, const float* w3,
                       const float* w4, const float* w5, const float* w6, const float* w7,
                       unsigned short* t0, unsigned short* t1, unsigned short* t2,
                       unsigned short* t3, unsigned short* t4, unsigned short* t5,
                       unsigned short* t6, unsigned short* t7,
                       const float4* __restrict__ x, uint2* __restrict__ xb, int n4) {
  int m = blockIdx.y;
  int stride = gridDim.x * blockDim.x;
  int start = blockIdx.x * blockDim.x + threadIdx.x;
  if (m == 8) {
    for (int i = start; i < n4; i += stride) {
      float4 v = x[i];
      uint2 o;
      o.x = pack_bf16_2(v.x, v.y);
      o.y = pack_bf16_2(v.z, v.w);
      xb[i] = o;
    }
    return;
  }
  const float* W;
  unsigned short* T;
  switch (m) {
    case 0: W = w0; T = t0; break;
    case 1: W = w1; T = t1; break;
    case 2: W = w2; T = t2; break;
    case 3: W = w3; T = t3; break;
    case 4: W = w4; T = t4; break;
    case 5: W = w5; T = t5; break;
    case 6: W = w6; T = t6; break;
    default: W = w7; T = t7; break;
  }
  int din = (m < 4) ? 64 : 128;
  int total = din * 128;
  for (int i = start; i < total; i += stride) {
    int r = i >> 7, c = i & 127;  // W[r][c]
    T[c * din + r] = bf16r(W[i]);
  }
}

// ---------------- bf16 MFMA 4-way linear ----------------
// grid (ceil(N/128), 4). y: 0=q(bf16, pre-scaled) 1=k(->kv lo) 2=v(->kv hi)
// 3=skip(fp32). 512 threads = 8 waves laid out 2(row)x4(col): wave owns
// 64 rows x 32 cols. A-frags preloaded (4 per ks); in-loop: 1 B ds_read per
// 4 MFMA (was 1:1 in R7).

template <int DIN>
__global__ __launch_bounds__(512) void gemm4(
    const unsigned short* __restrict__ xb, int N,
    const unsigned short* __restrict__ Wt0, const float* __restrict__ B0,
    const unsigned short* __restrict__ Wt1, const float* __restrict__ B1,
    const unsigned short* __restrict__ Wt2, const float* __restrict__ B2,
    const unsigned short* __restrict__ Wt3, const float* __restrict__ B3,
    unsigned short* __restrict__ Qb, unsigned short* __restrict__ KV,
    float* __restrict__ Os) {
  constexpr int DS = DIN + 8;
  __shared__ __align__(16) unsigned short As[128 * DS];
  __shared__ __align__(16) unsigned short Bs[128 * DS];
  const unsigned short* Wt;
  const float* Bias;
  int y = blockIdx.y;
  switch (y) {
    case 0: Wt = Wt0; Bias = B0; break;
    case 1: Wt = Wt1; Bias = B1; break;
    case 2: Wt = Wt2; Bias = B2; break;
    default: Wt = Wt3; Bias = B3; break;
  }
  int tid = threadIdx.x;
  int n0 = blockIdx.x * 128;

  constexpr int CPR = DIN / 8;          // 16B chunks per row
  constexpr int ACH = 128 * CPR;        // chunks per tile
#pragma unroll
  for (int c = tid; c < ACH; c += 512) {
    int row = c / CPR, c8 = c - row * CPR;
    int n = n0 + row;
    uint4 val = {0u, 0u, 0u, 0u};
    if (n < N) val = *(const uint4*)&xb[(size_t)n * DIN + c8 * 8];
    *(uint4*)&As[row * DS + c8 * 8] = val;
  }
#pragma unroll
  for (int c = tid; c < ACH; c += 512) {
    int row = c / CPR, c8 = c - row * CPR;
    uint4 val = *(const uint4*)&Wt[(size_t)row * DIN + c8 * 8];
    *(uint4*)&Bs[row * DS + c8 * 8] = val;
  }
  __syncthreads();

  int w = tid >> 6, lane = tid & 63, lr = lane & 15, lg = lane >> 4;
  int wr = w >> 2;           // row half: rows wr*64 .. wr*64+63
  int wc = w & 3;            // col quarter: cols wc*32 .. wc*32+31
  constexpr int KS = DIN / 32;

  short8v a[4][KS];
#pragma unroll
  for (int af = 0; af < 4; ++af)
#pragma unroll
    for (int ks = 0; ks < KS; ++ks)
      a[af][ks] = *(const short8v*)&As[(wr * 64 + af * 16 + lr) * DS + ks * 32 + lg * 8];

  f32x4 acc[4][2];
#pragma unroll
  for (int af = 0; af < 4; ++af)
#pragma unroll
    for (int nf = 0; nf < 2; ++nf) acc[af][nf] = (f32x4){0.f, 0.f, 0.f, 0.f};

#pragma unroll
  for (int ks = 0; ks < KS; ++ks) {
#pragma unroll
    for (int nf = 0; nf < 2; ++nf) {
      short8v b = *(const short8v*)&Bs[(wc * 32 + nf * 16 + lr) * DS + ks * 32 + lg * 8];
#pragma unroll
      for (int af = 0; af < 4; ++af)
        acc[af][nf] = __builtin_amdgcn_mfma_f32_16x16x32_bf16(a[af][ks], b, acc[af][nf], 0, 0, 0);
    }
  }

#pragma unroll
  for (int af = 0; af < 4; ++af) {
    int rbase = n0 + wr * 64 + af * 16 + lg * 4;
#pragma unroll
    for (int nf = 0; nf < 2; ++nf) {
      int col = wc * 32 + nf * 16 + lr;
      float bias = Bias[col];
      if (y == 0) {
#pragma unroll
        for (int r = 0; r < 4; ++r) {
          int n = rbase + r;
          if (n < N) Qb[(size_t)n * 128 + col] = bf16r((acc[af][nf][r] + bias) * QSCALE);
        }
      } else if (y == 3) {
#pragma unroll
        for (int r = 0; r < 4; ++r) {
          int n = rbase + r;
          if (n < N) Os[(size_t)n * 128 + col] = acc[af][nf][r] + bias;
        }
      } else {
        int off = (col >> 2) * 8 + (col & 3) + ((y == 2) ? 4 : 0);
#pragma unroll
        for (int r = 0; r < 4; ++r) {
          int n = rbase + r;
          if (n < N) KV[(size_t)n * 256 + off] = bf16r(acc[af][nf][r] + bias);
        }
      }
    }
  }
}

// ---------------- edge aggregation ----------------
// One wave per dst node; 2 x 32-lane deferred-max online-softmax streams over
// alternating edges (prefetch depth 3), merged at end.
// kv slot l = {k[4l..4l+3], v[4l..4l+3]} bf16; q bf16 pre-scaled.
// POOL: add (skip+agg)*cnt_inv[batch[n]] straight into out via atomics.

template <bool RELU, bool OUTBF16, bool POOL>
__global__ __launch_bounds__(256) void edge_agg2(
    const unsigned short* __restrict__ qb, const uint4* __restrict__ kv,
    const int* __restrict__ rowptr, const int* __restrict__ csr_src,
    const float* skip, void* outp, const int* __restrict__ batch,
    const float* __restrict__ cnt_inv, int N) {
  int tid = threadIdx.x;
  int lane = tid & 63;
  int wv = tid >> 6;
  int n = blockIdx.x * 4 + wv;
  if (n >= N) return;
  int g = lane >> 5;
  int l = lane & 31;
  int gg = 0;
  if (POOL) gg = batch[n];
  uint2 qp = *(const uint2*)&qb[(size_t)n * 128 + 4 * l];
  float qx = __uint_as_float(qp.x << 16);
  float qy = __uint_as_float(qp.x & 0xffff0000u);
  float qz = __uint_as_float(qp.y << 16);
  float qw = __uint_as_float(qp.y & 0xffff0000u);
  int beg = rowptr[n];
  int deg = rowptr[n + 1] - beg;
  float m = -INFINITY, lsum = 0.f;
  float a0 = 0.f, a1 = 0.f, a2 = 0.f, a3 = 0.f;
  int cnt = (deg - g + 1) >> 1;
  const int* cp = csr_src + beg + g;
  uint4 kv0 = {0, 0, 0, 0}, kv1 = {0, 0, 0, 0}, kv2 = {0, 0, 0, 0};
  if (cnt >= 1) kv0 = kv[(size_t)cp[0] * 32 + l];
  if (cnt >= 2) kv1 = kv[(size_t)cp[2] * 32 + l];
  if (cnt >= 3) kv2 = kv[(size_t)cp[4] * 32 + l];
  for (int it = 0; it < cnt; ++it) {
    uint4 cur = kv0;
    kv0 = kv1;
    kv1 = kv2;
    if (it + 3 < cnt) kv2 = kv[(size_t)cp[2 * (it + 3)] * 32 + l];
    float k0 = __uint_as_float(cur.x << 16);
    float k1 = __uint_as_float(cur.x & 0xffff0000u);
    float k2 = __uint_as_float(cur.y << 16);
    float k3 = __uint_as_float(cur.y & 0xffff0000u);
    float d = qx * k0 + qy * k1 + qz * k2 + qw * k3;
#pragma unroll
    for (int off = 1; off < 32; off <<= 1) d += __shfl_xor(d, off);
    float v0 = __uint_as_float(cur.z << 16);
    float v1 = __uint_as_float(cur.z & 0xffff0000u);
    float v2 = __uint_as_float(cur.w << 16);
    float v3 = __uint_as_float(cur.w & 0xffff0000u);
    if (d > m + 8.f) {        // rare: new max beyond slack -> rescale
      float cf = __expf(m - d);
      lsum = lsum * cf + 1.f;
      a0 = a0 * cf + v0;
      a1 = a1 * cf + v1;
      a2 = a2 * cf + v2;
      a3 = a3 * cf + v3;
      m = d;
    } else {                  // common: accumulate against stale max
      float ef = __expf(d - m);
      lsum += ef;
      a0 += ef * v0;
      a1 += ef * v1;
      a2 += ef * v2;
      a3 += ef * v3;
    }
  }
  float m2 = __shfl_xor(m, 32);
  float L2 = __shfl_xor(lsum, 32);
  float b0 = __shfl_xor(a0, 32);
  float b1 = __shfl_xor(a1, 32);
  float b2 = __shfl_xor(a2, 32);
  float b3 = __shfl_xor(a3, 32);
  if (lane < 32) {
    float ox0 = 0.f, ox1 = 0.f, ox2 = 0.f, ox3 = 0.f;
    if (deg > 0) {
      float M = fmaxf(m, m2);
      float c1 = __expf(m - M);
      float c2 = __expf(m2 - M);
      float rl = 1.f / (lsum * c1 + L2 * c2 + 1e-16f);
      ox0 = (a0 * c1 + b0 * c2) * rl;
      ox1 = (a1 * c1 + b1 * c2) * rl;
      ox2 = (a2 * c1 + b2 * c2) * rl;
      ox3 = (a3 * c1 + b3 * c2) * rl;
    }
    const float* sp = skip + (size_t)n * 128 + 4 * l;
    float4 o = *(const float4*)sp;
    o.x += ox0; o.y += ox1; o.z += ox2; o.w += ox3;
    if (RELU) {
      o.x = fmaxf(o.x, 0.f);
      o.y = fmaxf(o.y, 0.f);
      o.z = fmaxf(o.z, 0.f);
      o.w = fmaxf(o.w, 0.f);
    }
    if (POOL) {
      float ci = cnt_inv[gg];
      float* ob = (float*)outp + (size_t)gg * 128 + 4 * l;
      atomicAdd(&ob[0], o.x * ci);
      atomicAdd(&ob[1], o.y * ci);
      atomicAdd(&ob[2], o.z * ci);
      atomicAdd(&ob[3], o.w * ci);
    } else if (OUTBF16) {
      unsigned short* ob = (unsigned short*)outp + (size_t)n * 128 + 4 * l;
      uint2 pk;
      pk.x = pack_bf16_2(o.x, o.y);
      pk.y = pack_bf16_2(o.z, o.w);
      *(uint2*)ob = pk;
    } else {
      float* of = (float*)outp + (size_t)n * 128 + 4 * l;
      *(float4*)of = o;
    }
  }
}

// ---------------- launch ----------------

extern "C" void kernel_launch(void* const* d_in, const int* in_sizes, int n_in,
                              void* d_out, int out_size, void* d_ws, size_t ws_size,
                              hipStream_t stream) {
  const float* x = (const float*)d_in[0];
  const int* ei = (const int*)d_in[1];
  const int* batch = (const int*)d_in[2];
  const float* Wq1 = (const float*)d_in[3];
  const float* bq1 = (const float*)d_in[4];
  const float* Wk1 = (const float*)d_in[5];
  const float* bk1 = (const float*)d_in[6];
  const float* Wv1 = (const float*)d_in[7];
  const float* bv1 = (const float*)d_in[8];
  const float* Ws1 = (const float*)d_in[9];
  const float* bs1 = (const float*)d_in[10];
  const float* Wq2 = (const float*)d_in[11];
  const float* bq2 = (const float*)d_in[12];
  const float* Wk2 = (const float*)d_in[13];
  const float* bk2 = (const float*)d_in[14];
  const float* Wv2 = (const float*)d_in[15];
  const float* bv2 = (const float*)d_in[16];
  const float* Ws2 = (const float*)d_in[17];
  const float* bs2 = (const float*)d_in[18];

  int N = in_sizes[0] / D1;  // 50000
  int E = in_sizes[1] / 2;   // 800000
  int NG = out_size / DH;    // 512
  const int* src = ei;
  const int* dst = ei + E;

  char* ws = (char*)d_ws;
  unsigned short* qb = (unsigned short*)ws;  ws += (size_t)N * DH * 2;  // bf16 q (pre-scaled)
  unsigned short* kvb = (unsigned short*)ws; ws += (size_t)N * DH * 4;  // bf16 k|v interleaved
  float* s = (float*)ws;             ws += (size_t)N * DH * 4;   // skip
  unsigned short* h1b = (unsigned short*)ws; ws += (size_t)N * DH * 2;  // bf16 h1
  unsigned short* xb = (unsigned short*)ws;  ws += (size_t)N * D1 * 2;  // bf16 x
  unsigned short* wt[8];
  for (int m = 0; m < 8; ++m) {
    int din = (m < 4) ? 64 : 128;
    wt[m] = (unsigned short*)ws;
    ws += (size_t)128 * din * 2;
  }
  ws = (char*)(((size_t)ws + 255) & ~(size_t)255);
  float* cnt_inv = (float*)ws; ws += 2048;
  int* rowptr = (int*)ws; ws += (size_t)(N + 1) * 4;
  ws = (char*)(((size_t)ws + 255) & ~(size_t)255);
  int* deg = (int*)ws;  ws += (size_t)N * 4;
  int* fill = (int*)ws; ws += (size_t)N * 4;   // contiguous with deg: one memset
  int* incl = (int*)ws; ws += (size_t)N * 4;
  int* sums = (int*)ws; ws += 1024;
  int* csr = (int*)ws;  ws += (size_t)E * 4;

  int nch = (N + SCHUNK - 1) / SCHUNK;

  hipMemsetAsync(deg, 0, (size_t)2 * N * 4, stream);   // deg + fill
  hipMemsetAsync(d_out, 0, (size_t)out_size * 4, stream);  // pool accumulators

  hist_kernel<<<(E + 255) / 256, 256, 0, stream>>>(dst, deg, E);
  scan_chunks<<<nch, 256, 0, stream>>>(deg, incl, sums, N);
  finalize_rowptr<<<(N + 255) / 256, 256, 0, stream>>>(incl, sums, rowptr, N,
                                                       batch, cnt_inv, NG);
  fill_csr<<<(E + 255) / 256, 256, 0, stream>>>(src, dst, rowptr, fill, csr, E);

  prep_w<<<dim3(64, 9), 256, 0, stream>>>(Wq1, Wk1, Wv1, Ws1, Wq2, Wk2, Wv2, Ws2,
                                          wt[0], wt[1], wt[2], wt[3],
                                          wt[4], wt[5], wt[6], wt[7],
                                          (const float4*)x, (uint2*)xb, N * D1 / 4);

  int nb = (N + 127) / 128;
  // layer 1
  gemm4<D1><<<dim3(nb, 4), 512, 0, stream>>>(xb, N, wt[0], bq1, wt[1], bk1,
                                             wt[2], bv1, wt[3], bs1, qb, kvb, s);
  edge_agg2<true, true, false><<<(N + 3) / 4, 256, 0, stream>>>(
      qb, (const uint4*)kvb, rowptr, csr, s, h1b, batch, cnt_inv, N);
  // layer 2
  gemm4<DH><<<dim3(nb, 4), 512, 0, stream>>>(h1b, N, wt[4], bq2, wt[5], bk2,
                                             wt[6], bv2, wt[7], bs2, qb, kvb, s);
  // layer-2 aggregation fused with global mean pool (pre-divided atomics)
  edge_agg2<false, false, true><<<(N + 3) / 4, 256, 0, stream>>>(
      qb, (const uint4*)kvb, rowptr, csr, s, d_out, batch, cnt_inv, N);
}

// Round 10
// 340.321 us; speedup vs baseline: 1.1106x; 1.1106x over previous
//
#include <hip/hip_runtime.h>
#include <math.h>

// DrugEncoder: 2x TransformerConv (heads=1) + global mean pool.
// N=50000 nodes, E=800000 edges, G=512 graphs, D_IN=64, D_HID=D_EMB=128.
//
// R10: R8's re-tiled gemm4 kept; atomic pool-fusion REVERTED (R9: 6.4M atomics
//      on 4096 lines quadrupled write traffic, edge_agg 67->126us). Layer-2
//      edge_agg writes fp32 in-place; separate pool kernel.

constexpr int D1 = 64;
constexpr int DH = 128;
constexpr int SCHUNK = 1024;
constexpr float QSCALE = 0.08838834764831845f;  // 1/sqrt(128)

typedef __attribute__((ext_vector_type(8))) short short8v;
typedef __attribute__((ext_vector_type(4))) float f32x4;

__device__ inline unsigned short bf16r(float f) {
  unsigned u = __float_as_uint(f);
  return (unsigned short)((u + 0x7fffu + ((u >> 16) & 1u)) >> 16);
}

__device__ inline unsigned pack_bf16_2(float a, float b) {
  return (unsigned)bf16r(a) | ((unsigned)bf16r(b) << 16);
}

// ---------------- CSR build ----------------

__global__ void hist_kernel(const int* __restrict__ dst, int* __restrict__ deg, int E) {
  int e = blockIdx.x * blockDim.x + threadIdx.x;
  if (e < E) atomicAdd(&deg[dst[e]], 1);
}

__global__ void scan_chunks(const int* __restrict__ deg, int* __restrict__ incl,
                            int* __restrict__ sums, int N) {
  __shared__ int lds[256];
  int b = blockIdx.x, tid = threadIdx.x;
  int base = b * SCHUNK + tid * 4;
  int e0 = (base + 0 < N) ? deg[base + 0] : 0;
  int e1 = (base + 1 < N) ? deg[base + 1] : 0;
  int e2 = (base + 2 < N) ? deg[base + 2] : 0;
  int e3 = (base + 3 < N) ? deg[base + 3] : 0;
  int t0 = e0, t1 = t0 + e1, t2 = t1 + e2, t3 = t2 + e3;
  lds[tid] = t3;
  __syncthreads();
  for (int off = 1; off < 256; off <<= 1) {
    int v = (tid >= off) ? lds[tid - off] : 0;
    __syncthreads();
    lds[tid] += v;
    __syncthreads();
  }
  int excl = (tid > 0) ? lds[tid - 1] : 0;
  if (base + 0 < N) incl[base + 0] = t0 + excl;
  if (base + 1 < N) incl[base + 1] = t1 + excl;
  if (base + 2 < N) incl[base + 2] = t2 + excl;
  if (base + 3 < N) incl[base + 3] = t3 + excl;
  if (tid == 255) sums[b] = lds[255];
}

// rowptr[n+1] = incl[n] + sum(sums[0..n/SCHUNK)); ~49 L2-hit adds per thread.
__global__ void finalize_rowptr(const int* __restrict__ incl, const int* __restrict__ sums,
                                int* __restrict__ rowptr, int N) {
  int n = blockIdx.x * blockDim.x + threadIdx.x;
  if (n < N) {
    int ch = n / SCHUNK;
    int off = 0;
    for (int i = 0; i < ch; ++i) off += sums[i];
    rowptr[n + 1] = incl[n] + off;
  }
  if (n == 0) rowptr[0] = 0;
}

__global__ void fill_csr(const int* __restrict__ src, const int* __restrict__ dst,
                         const int* __restrict__ rowptr, int* __restrict__ fill,
                         int* __restrict__ csr_src, int E) {
  int e = blockIdx.x * blockDim.x + threadIdx.x;
  if (e < E) {
    int d = dst[e];
    int pos = rowptr[d] + atomicAdd(&fill[d], 1);
    csr_src[pos] = src[e];
  }
}

// ---------------- prep: W -> transposed bf16 (y<8), x -> bf16 (y==8) ----------------

__global__ void prep_w(const float* w0, const float* w1, const float* w2, const float* w3,
                       const float* w4, const float* w5, const float* w6, const float* w7,
                       unsigned short* t0, unsigned short* t1, unsigned short* t2,
                       unsigned short* t3, unsigned short* t4, unsigned short* t5,
                       unsigned short* t6, unsigned short* t7,
                       const float4* __restrict__ x, uint2* __restrict__ xb, int n4) {
  int m = blockIdx.y;
  int stride = gridDim.x * blockDim.x;
  int start = blockIdx.x * blockDim.x + threadIdx.x;
  if (m == 8) {
    for (int i = start; i < n4; i += stride) {
      float4 v = x[i];
      uint2 o;
      o.x = pack_bf16_2(v.x, v.y);
      o.y = pack_bf16_2(v.z, v.w);
      xb[i] = o;
    }
    return;
  }
  const float* W;
  unsigned short* T;
  switch (m) {
    case 0: W = w0; T = t0; break;
    case 1: W = w1; T = t1; break;
    case 2: W = w2; T = t2; break;
    case 3: W = w3; T = t3; break;
    case 4: W = w4; T = t4; break;
    case 5: W = w5; T = t5; break;
    case 6: W = w6; T = t6; break;
    default: W = w7; T = t7; break;
  }
  int din = (m < 4) ? 64 : 128;
  int total = din * 128;
  for (int i = start; i < total; i += stride) {
    int r = i >> 7, c = i & 127;  // W[r][c]
    T[c * din + r] = bf16r(W[i]);
  }
}

// ---------------- bf16 MFMA 4-way linear ----------------
// grid (ceil(N/128), 4). y: 0=q(bf16, pre-scaled) 1=k(->kv lo) 2=v(->kv hi)
// 3=skip(fp32). 512 threads = 8 waves laid out 2(row)x4(col): wave owns
// 64 rows x 32 cols. A-frags preloaded (4 per ks); in-loop: 1 B ds_read per
// 4 MFMA.

template <int DIN>
__global__ __launch_bounds__(512) void gemm4(
    const unsigned short* __restrict__ xb, int N,
    const unsigned short* __restrict__ Wt0, const float* __restrict__ B0,
    const unsigned short* __restrict__ Wt1, const float* __restrict__ B1,
    const unsigned short* __restrict__ Wt2, const float* __restrict__ B2,
    const unsigned short* __restrict__ Wt3, const float* __restrict__ B3,
    unsigned short* __restrict__ Qb, unsigned short* __restrict__ KV,
    float* __restrict__ Os) {
  constexpr int DS = DIN + 8;
  __shared__ __align__(16) unsigned short As[128 * DS];
  __shared__ __align__(16) unsigned short Bs[128 * DS];
  const unsigned short* Wt;
  const float* Bias;
  int y = blockIdx.y;
  switch (y) {
    case 0: Wt = Wt0; Bias = B0; break;
    case 1: Wt = Wt1; Bias = B1; break;
    case 2: Wt = Wt2; Bias = B2; break;
    default: Wt = Wt3; Bias = B3; break;
  }
  int tid = threadIdx.x;
  int n0 = blockIdx.x * 128;

  constexpr int CPR = DIN / 8;          // 16B chunks per row
  constexpr int ACH = 128 * CPR;        // chunks per tile
#pragma unroll
  for (int c = tid; c < ACH; c += 512) {
    int row = c / CPR, c8 = c - row * CPR;
    int n = n0 + row;
    uint4 val = {0u, 0u, 0u, 0u};
    if (n < N) val = *(const uint4*)&xb[(size_t)n * DIN + c8 * 8];
    *(uint4*)&As[row * DS + c8 * 8] = val;
  }
#pragma unroll
  for (int c = tid; c < ACH; c += 512) {
    int row = c / CPR, c8 = c - row * CPR;
    uint4 val = *(const uint4*)&Wt[(size_t)row * DIN + c8 * 8];
    *(uint4*)&Bs[row * DS + c8 * 8] = val;
  }
  __syncthreads();

  int w = tid >> 6, lane = tid & 63, lr = lane & 15, lg = lane >> 4;
  int wr = w >> 2;           // row half: rows wr*64 .. wr*64+63
  int wc = w & 3;            // col quarter: cols wc*32 .. wc*32+31
  constexpr int KS = DIN / 32;

  short8v a[4][KS];
#pragma unroll
  for (int af = 0; af < 4; ++af)
#pragma unroll
    for (int ks = 0; ks < KS; ++ks)
      a[af][ks] = *(const short8v*)&As[(wr * 64 + af * 16 + lr) * DS + ks * 32 + lg * 8];

  f32x4 acc[4][2];
#pragma unroll
  for (int af = 0; af < 4; ++af)
#pragma unroll
    for (int nf = 0; nf < 2; ++nf) acc[af][nf] = (f32x4){0.f, 0.f, 0.f, 0.f};

#pragma unroll
  for (int ks = 0; ks < KS; ++ks) {
#pragma unroll
    for (int nf = 0; nf < 2; ++nf) {
      short8v b = *(const short8v*)&Bs[(wc * 32 + nf * 16 + lr) * DS + ks * 32 + lg * 8];
#pragma unroll
      for (int af = 0; af < 4; ++af)
        acc[af][nf] = __builtin_amdgcn_mfma_f32_16x16x32_bf16(a[af][ks], b, acc[af][nf], 0, 0, 0);
    }
  }

#pragma unroll
  for (int af = 0; af < 4; ++af) {
    int rbase = n0 + wr * 64 + af * 16 + lg * 4;
#pragma unroll
    for (int nf = 0; nf < 2; ++nf) {
      int col = wc * 32 + nf * 16 + lr;
      float bias = Bias[col];
      if (y == 0) {
#pragma unroll
        for (int r = 0; r < 4; ++r) {
          int n = rbase + r;
          if (n < N) Qb[(size_t)n * 128 + col] = bf16r((acc[af][nf][r] + bias) * QSCALE);
        }
      } else if (y == 3) {
#pragma unroll
        for (int r = 0; r < 4; ++r) {
          int n = rbase + r;
          if (n < N) Os[(size_t)n * 128 + col] = acc[af][nf][r] + bias;
        }
      } else {
        int off = (col >> 2) * 8 + (col & 3) + ((y == 2) ? 4 : 0);
#pragma unroll
        for (int r = 0; r < 4; ++r) {
          int n = rbase + r;
          if (n < N) KV[(size_t)n * 256 + off] = bf16r(acc[af][nf][r] + bias);
        }
      }
    }
  }
}

// ---------------- edge aggregation ----------------
// One wave per dst node; 2 x 32-lane deferred-max online-softmax streams over
// alternating edges (prefetch depth 3), merged at end.
// kv slot l = {k[4l..4l+3], v[4l..4l+3]} bf16; q bf16 pre-scaled.

template <bool RELU, bool OUTBF16>
__global__ __launch_bounds__(256) void edge_agg2(
    const unsigned short* __restrict__ qb, const uint4* __restrict__ kv,
    const int* __restrict__ rowptr, const int* __restrict__ csr_src,
    const float* skip, void* outp, int N) {
  int tid = threadIdx.x;
  int lane = tid & 63;
  int wv = tid >> 6;
  int n = blockIdx.x * 4 + wv;
  if (n >= N) return;
  int g = lane >> 5;
  int l = lane & 31;
  uint2 qp = *(const uint2*)&qb[(size_t)n * 128 + 4 * l];
  float qx = __uint_as_float(qp.x << 16);
  float qy = __uint_as_float(qp.x & 0xffff0000u);
  float qz = __uint_as_float(qp.y << 16);
  float qw = __uint_as_float(qp.y & 0xffff0000u);
  int beg = rowptr[n];
  int deg = rowptr[n + 1] - beg;
  float m = -INFINITY, lsum = 0.f;
  float a0 = 0.f, a1 = 0.f, a2 = 0.f, a3 = 0.f;
  int cnt = (deg - g + 1) >> 1;
  const int* cp = csr_src + beg + g;
  uint4 kv0 = {0, 0, 0, 0}, kv1 = {0, 0, 0, 0}, kv2 = {0, 0, 0, 0};
  if (cnt >= 1) kv0 = kv[(size_t)cp[0] * 32 + l];
  if (cnt >= 2) kv1 = kv[(size_t)cp[2] * 32 + l];
  if (cnt >= 3) kv2 = kv[(size_t)cp[4] * 32 + l];
  for (int it = 0; it < cnt; ++it) {
    uint4 cur = kv0;
    kv0 = kv1;
    kv1 = kv2;
    if (it + 3 < cnt) kv2 = kv[(size_t)cp[2 * (it + 3)] * 32 + l];
    float k0 = __uint_as_float(cur.x << 16);
    float k1 = __uint_as_float(cur.x & 0xffff0000u);
    float k2 = __uint_as_float(cur.y << 16);
    float k3 = __uint_as_float(cur.y & 0xffff0000u);
    float d = qx * k0 + qy * k1 + qz * k2 + qw * k3;
#pragma unroll
    for (int off = 1; off < 32; off <<= 1) d += __shfl_xor(d, off);
    float v0 = __uint_as_float(cur.z << 16);
    float v1 = __uint_as_float(cur.z & 0xffff0000u);
    float v2 = __uint_as_float(cur.w << 16);
    float v3 = __uint_as_float(cur.w & 0xffff0000u);
    if (d > m + 8.f) {        // rare: new max beyond slack -> rescale
      float cf = __expf(m - d);
      lsum = lsum * cf + 1.f;
      a0 = a0 * cf + v0;
      a1 = a1 * cf + v1;
      a2 = a2 * cf + v2;
      a3 = a3 * cf + v3;
      m = d;
    } else {                  // common: accumulate against stale max
      float ef = __expf(d - m);
      lsum += ef;
      a0 += ef * v0;
      a1 += ef * v1;
      a2 += ef * v2;
      a3 += ef * v3;
    }
  }
  float m2 = __shfl_xor(m, 32);
  float L2 = __shfl_xor(lsum, 32);
  float b0 = __shfl_xor(a0, 32);
  float b1 = __shfl_xor(a1, 32);
  float b2 = __shfl_xor(a2, 32);
  float b3 = __shfl_xor(a3, 32);
  if (lane < 32) {
    float ox0 = 0.f, ox1 = 0.f, ox2 = 0.f, ox3 = 0.f;
    if (deg > 0) {
      float M = fmaxf(m, m2);
      float c1 = __expf(m - M);
      float c2 = __expf(m2 - M);
      float rl = 1.f / (lsum * c1 + L2 * c2 + 1e-16f);
      ox0 = (a0 * c1 + b0 * c2) * rl;
      ox1 = (a1 * c1 + b1 * c2) * rl;
      ox2 = (a2 * c1 + b2 * c2) * rl;
      ox3 = (a3 * c1 + b3 * c2) * rl;
    }
    const float* sp = skip + (size_t)n * 128 + 4 * l;
    float4 o = *(const float4*)sp;
    o.x += ox0; o.y += ox1; o.z += ox2; o.w += ox3;
    if (RELU) {
      o.x = fmaxf(o.x, 0.f);
      o.y = fmaxf(o.y, 0.f);
      o.z = fmaxf(o.z, 0.f);
      o.w = fmaxf(o.w, 0.f);
    }
    if (OUTBF16) {
      unsigned short* ob = (unsigned short*)outp + (size_t)n * 128 + 4 * l;
      uint2 pk;
      pk.x = pack_bf16_2(o.x, o.y);
      pk.y = pack_bf16_2(o.z, o.w);
      *(uint2*)ob = pk;
    } else {
      float* of = (float*)outp + (size_t)n * 128 + 4 * l;
      *(float4*)of = o;
    }
  }
}

// ---------------- global mean pool (batch sorted) ----------------

__global__ __launch_bounds__(128) void pool_kernel(const float* __restrict__ h,
                                                   const int* __restrict__ batch,
                                                   float* __restrict__ out, int N) {
  int g = blockIdx.x;
  int lo = 0, hi = N;
  while (lo < hi) { int mid = (lo + hi) >> 1; if (batch[mid] < g) lo = mid + 1; else hi = mid; }
  int s0 = lo;
  hi = N;
  while (lo < hi) { int mid = (lo + hi) >> 1; if (batch[mid] <= g) lo = mid + 1; else hi = mid; }
  int s1 = lo;
  int j = threadIdx.x;
  float acc = 0.f;
  for (int n = s0; n < s1; ++n) acc += h[(size_t)n * 128 + j];
  out[(size_t)g * 128 + j] = acc / fmaxf((float)(s1 - s0), 1.f);
}

// ---------------- launch ----------------

extern "C" void kernel_launch(void* const* d_in, const int* in_sizes, int n_in,
                              void* d_out, int out_size, void* d_ws, size_t ws_size,
                              hipStream_t stream) {
  const float* x = (const float*)d_in[0];
  const int* ei = (const int*)d_in[1];
  const int* batch = (const int*)d_in[2];
  const float* Wq1 = (const float*)d_in[3];
  const float* bq1 = (const float*)d_in[4];
  const float* Wk1 = (const float*)d_in[5];
  const float* bk1 = (const float*)d_in[6];
  const float* Wv1 = (const float*)d_in[7];
  const float* bv1 = (const float*)d_in[8];
  const float* Ws1 = (const float*)d_in[9];
  const float* bs1 = (const float*)d_in[10];
  const float* Wq2 = (const float*)d_in[11];
  const float* bq2 = (const float*)d_in[12];
  const float* Wk2 = (const float*)d_in[13];
  const float* bk2 = (const float*)d_in[14];
  const float* Wv2 = (const float*)d_in[15];
  const float* bv2 = (const float*)d_in[16];
  const float* Ws2 = (const float*)d_in[17];
  const float* bs2 = (const float*)d_in[18];

  int N = in_sizes[0] / D1;  // 50000
  int E = in_sizes[1] / 2;   // 800000
  int NG = out_size / DH;    // 512
  const int* src = ei;
  const int* dst = ei + E;

  char* ws = (char*)d_ws;
  unsigned short* qb = (unsigned short*)ws;  ws += (size_t)N * DH * 2;  // bf16 q (pre-scaled)
  unsigned short* kvb = (unsigned short*)ws; ws += (size_t)N * DH * 4;  // bf16 k|v interleaved
  float* s = (float*)ws;             ws += (size_t)N * DH * 4;   // skip / h2 (in-place)
  unsigned short* h1b = (unsigned short*)ws; ws += (size_t)N * DH * 2;  // bf16 h1
  unsigned short* xb = (unsigned short*)ws;  ws += (size_t)N * D1 * 2;  // bf16 x
  unsigned short* wt[8];
  for (int m = 0; m < 8; ++m) {
    int din = (m < 4) ? 64 : 128;
    wt[m] = (unsigned short*)ws;
    ws += (size_t)128 * din * 2;
  }
  ws = (char*)(((size_t)ws + 255) & ~(size_t)255);
  int* rowptr = (int*)ws; ws += (size_t)(N + 1) * 4;
  ws = (char*)(((size_t)ws + 255) & ~(size_t)255);
  int* deg = (int*)ws;  ws += (size_t)N * 4;
  int* fill = (int*)ws; ws += (size_t)N * 4;   // contiguous with deg: one memset
  int* incl = (int*)ws; ws += (size_t)N * 4;
  int* sums = (int*)ws; ws += 1024;
  int* csr = (int*)ws;  ws += (size_t)E * 4;

  int nch = (N + SCHUNK - 1) / SCHUNK;

  hipMemsetAsync(deg, 0, (size_t)2 * N * 4, stream);  // deg + fill

  hist_kernel<<<(E + 255) / 256, 256, 0, stream>>>(dst, deg, E);
  scan_chunks<<<nch, 256, 0, stream>>>(deg, incl, sums, N);
  finalize_rowptr<<<(N + 255) / 256, 256, 0, stream>>>(incl, sums, rowptr, N);
  fill_csr<<<(E + 255) / 256, 256, 0, stream>>>(src, dst, rowptr, fill, csr, E);

  prep_w<<<dim3(64, 9), 256, 0, stream>>>(Wq1, Wk1, Wv1, Ws1, Wq2, Wk2, Wv2, Ws2,
                                          wt[0], wt[1], wt[2], wt[3],
                                          wt[4], wt[5], wt[6], wt[7],
                                          (const float4*)x, (uint2*)xb, N * D1 / 4);

  int nb = (N + 127) / 128;
  // layer 1
  gemm4<D1><<<dim3(nb, 4), 512, 0, stream>>>(xb, N, wt[0], bq1, wt[1], bk1,
                                             wt[2], bv1, wt[3], bs1, qb, kvb, s);
  edge_agg2<true, true><<<(N + 3) / 4, 256, 0, stream>>>(
      qb, (const uint4*)kvb, rowptr, csr, s, h1b, N);
  // layer 2
  gemm4<DH><<<dim3(nb, 4), 512, 0, stream>>>(h1b, N, wt[4], bq2, wt[5], bk2,
                                             wt[6], bv2, wt[7], bs2, qb, kvb, s);
  edge_agg2<false, false><<<(N + 3) / 4, 256, 0, stream>>>(
      qb, (const uint4*)kvb, rowptr, csr, s, s, N);
  // mean pool
  pool_kernel<<<NG, 128, 0, stream>>>(s, batch, (float*)d_out, N);
}

// Round 11
// 336.926 us; speedup vs baseline: 1.1218x; 1.0101x over previous
//
#include <hip/hip_runtime.h>
#include <math.h>

// DrugEncoder: 2x TransformerConv (heads=1) + global mean pool.
// N=50000 nodes, E=800000 edges, G=512 graphs, D_IN=64, D_HID=D_EMB=128.
//
// R11: dependency-level fusion: {hist+prep_w} one dispatch; {fill_csr +
//      gemm4<64>} one dispatch (random-memory work overlaps MFMA work);
//      layer-2 output + pool in bf16. 8 dispatches total.

constexpr int D1 = 64;
constexpr int DH = 128;
constexpr int SCHUNK = 1024;
constexpr float QSCALE = 0.08838834764831845f;  // 1/sqrt(128)

typedef __attribute__((ext_vector_type(8))) short short8v;
typedef __attribute__((ext_vector_type(4))) float f32x4;

__device__ inline unsigned short bf16r(float f) {
  unsigned u = __float_as_uint(f);
  return (unsigned short)((u + 0x7fffu + ((u >> 16) & 1u)) >> 16);
}

__device__ inline unsigned pack_bf16_2(float a, float b) {
  return (unsigned)bf16r(a) | ((unsigned)bf16r(b) << 16);
}

__device__ inline float bf16f(unsigned short u) {
  return __uint_as_float(((unsigned)u) << 16);
}

// ---------------- level A: histogram + weight/x prep (independent) ----------------
// blocks [0, nbHist): dst histogram, 4 edges/thread via int4.
// blocks [nbHist, nbHist+512): W transpose+bf16 (m = g>>6, 64 blocks each).
// blocks [nbHist+512, nbHist+768): x -> bf16 (grid-stride).

__global__ __launch_bounds__(256) void hist_prep(
    const int* __restrict__ dst, int* __restrict__ deg, int E, int nbHist,
    const float* w0, const float* w1, const float* w2, const float* w3,
    const float* w4, const float* w5, const float* w6, const float* w7,
    unsigned short* t0, unsigned short* t1, unsigned short* t2,
    unsigned short* t3, unsigned short* t4, unsigned short* t5,
    unsigned short* t6, unsigned short* t7,
    const float4* __restrict__ x, uint2* __restrict__ xb, int n4) {
  int b = blockIdx.x;
  int tid = threadIdx.x;
  if (b < nbHist) {
    int i = b * 256 + tid;
    if (i < (E >> 2)) {
      int4 d4 = ((const int4*)dst)[i];
      atomicAdd(&deg[d4.x], 1);
      atomicAdd(&deg[d4.y], 1);
      atomicAdd(&deg[d4.z], 1);
      atomicAdd(&deg[d4.w], 1);
    }
    return;
  }
  int g = b - nbHist;
  if (g < 512) {
    int m = g >> 6, bx = g & 63;
    const float* W;
    unsigned short* T;
    switch (m) {
      case 0: W = w0; T = t0; break;
      case 1: W = w1; T = t1; break;
      case 2: W = w2; T = t2; break;
      case 3: W = w3; T = t3; break;
      case 4: W = w4; T = t4; break;
      case 5: W = w5; T = t5; break;
      case 6: W = w6; T = t6; break;
      default: W = w7; T = t7; break;
    }
    int din = (m < 4) ? 64 : 128;
    int total = din * 128;
    int i = bx * 256 + tid;
    if (i < total) {
      int r = i >> 7, c = i & 127;  // W[r][c]
      T[c * din + r] = bf16r(W[i]);
    }
    return;
  }
  int bx = g - 512;  // 256 blocks
  for (int i = bx * 256 + tid; i < n4; i += 256 * 256) {
    float4 v = x[i];
    uint2 o;
    o.x = pack_bf16_2(v.x, v.y);
    o.y = pack_bf16_2(v.z, v.w);
    xb[i] = o;
  }
}

// ---------------- CSR scan ----------------

__global__ void scan_chunks(const int* __restrict__ deg, int* __restrict__ incl,
                            int* __restrict__ sums, int N) {
  __shared__ int lds[256];
  int b = blockIdx.x, tid = threadIdx.x;
  int base = b * SCHUNK + tid * 4;
  int e0 = (base + 0 < N) ? deg[base + 0] : 0;
  int e1 = (base + 1 < N) ? deg[base + 1] : 0;
  int e2 = (base + 2 < N) ? deg[base + 2] : 0;
  int e3 = (base + 3 < N) ? deg[base + 3] : 0;
  int t0 = e0, t1 = t0 + e1, t2 = t1 + e2, t3 = t2 + e3;
  lds[tid] = t3;
  __syncthreads();
  for (int off = 1; off < 256; off <<= 1) {
    int v = (tid >= off) ? lds[tid - off] : 0;
    __syncthreads();
    lds[tid] += v;
    __syncthreads();
  }
  int excl = (tid > 0) ? lds[tid - 1] : 0;
  if (base + 0 < N) incl[base + 0] = t0 + excl;
  if (base + 1 < N) incl[base + 1] = t1 + excl;
  if (base + 2 < N) incl[base + 2] = t2 + excl;
  if (base + 3 < N) incl[base + 3] = t3 + excl;
  if (tid == 255) sums[b] = lds[255];
}

__global__ void finalize_rowptr(const int* __restrict__ incl, const int* __restrict__ sums,
                                int* __restrict__ rowptr, int N) {
  int n = blockIdx.x * blockDim.x + threadIdx.x;
  if (n < N) {
    int ch = n / SCHUNK;
    int off = 0;
    for (int i = 0; i < ch; ++i) off += sums[i];
    rowptr[n + 1] = incl[n] + off;
  }
  if (n == 0) rowptr[0] = 0;
}

// ---------------- bf16 MFMA 4-way linear (tile body) ----------------
// y: 0=q(bf16 pre-scaled) 1=k(->kv lo) 2=v(->kv hi) 3=skip(fp32).
// 512 threads = 8 waves, 2(row)x4(col): wave owns 64 rows x 32 cols;
// 1 B ds_read per 4 MFMA.

template <int DIN>
__device__ __forceinline__ void gemm4_tile(
    int bx, int y, int tid,
    const unsigned short* __restrict__ xb, int N,
    const unsigned short* __restrict__ Wt0, const float* __restrict__ B0,
    const unsigned short* __restrict__ Wt1, const float* __restrict__ B1,
    const unsigned short* __restrict__ Wt2, const float* __restrict__ B2,
    const unsigned short* __restrict__ Wt3, const float* __restrict__ B3,
    unsigned short* __restrict__ Qb, unsigned short* __restrict__ KV,
    float* __restrict__ Os) {
  constexpr int DS = DIN + 8;
  __shared__ __align__(16) unsigned short As[128 * DS];
  __shared__ __align__(16) unsigned short Bs[128 * DS];
  const unsigned short* Wt;
  const float* Bias;
  switch (y) {
    case 0: Wt = Wt0; Bias = B0; break;
    case 1: Wt = Wt1; Bias = B1; break;
    case 2: Wt = Wt2; Bias = B2; break;
    default: Wt = Wt3; Bias = B3; break;
  }
  int n0 = bx * 128;

  constexpr int CPR = DIN / 8;
  constexpr int ACH = 128 * CPR;
#pragma unroll
  for (int c = tid; c < ACH; c += 512) {
    int row = c / CPR, c8 = c - row * CPR;
    int n = n0 + row;
    uint4 val = {0u, 0u, 0u, 0u};
    if (n < N) val = *(const uint4*)&xb[(size_t)n * DIN + c8 * 8];
    *(uint4*)&As[row * DS + c8 * 8] = val;
  }
#pragma unroll
  for (int c = tid; c < ACH; c += 512) {
    int row = c / CPR, c8 = c - row * CPR;
    uint4 val = *(const uint4*)&Wt[(size_t)row * DIN + c8 * 8];
    *(uint4*)&Bs[row * DS + c8 * 8] = val;
  }
  __syncthreads();

  int w = tid >> 6, lane = tid & 63, lr = lane & 15, lg = lane >> 4;
  int wr = w >> 2;
  int wc = w & 3;
  constexpr int KS = DIN / 32;

  short8v a[4][KS];
#pragma unroll
  for (int af = 0; af < 4; ++af)
#pragma unroll
    for (int ks = 0; ks < KS; ++ks)
      a[af][ks] = *(const short8v*)&As[(wr * 64 + af * 16 + lr) * DS + ks * 32 + lg * 8];

  f32x4 acc[4][2];
#pragma unroll
  for (int af = 0; af < 4; ++af)
#pragma unroll
    for (int nf = 0; nf < 2; ++nf) acc[af][nf] = (f32x4){0.f, 0.f, 0.f, 0.f};

#pragma unroll
  for (int ks = 0; ks < KS; ++ks) {
#pragma unroll
    for (int nf = 0; nf < 2; ++nf) {
      short8v b = *(const short8v*)&Bs[(wc * 32 + nf * 16 + lr) * DS + ks * 32 + lg * 8];
#pragma unroll
      for (int af = 0; af < 4; ++af)
        acc[af][nf] = __builtin_amdgcn_mfma_f32_16x16x32_bf16(a[af][ks], b, acc[af][nf], 0, 0, 0);
    }
  }

#pragma unroll
  for (int af = 0; af < 4; ++af) {
    int rbase = n0 + wr * 64 + af * 16 + lg * 4;
#pragma unroll
    for (int nf = 0; nf < 2; ++nf) {
      int col = wc * 32 + nf * 16 + lr;
      float bias = Bias[col];
      if (y == 0) {
#pragma unroll
        for (int r = 0; r < 4; ++r) {
          int n = rbase + r;
          if (n < N) Qb[(size_t)n * 128 + col] = bf16r((acc[af][nf][r] + bias) * QSCALE);
        }
      } else if (y == 3) {
#pragma unroll
        for (int r = 0; r < 4; ++r) {
          int n = rbase + r;
          if (n < N) Os[(size_t)n * 128 + col] = acc[af][nf][r] + bias;
        }
      } else {
        int off = (col >> 2) * 8 + (col & 3) + ((y == 2) ? 4 : 0);
#pragma unroll
        for (int r = 0; r < 4; ++r) {
          int n = rbase + r;
          if (n < N) KV[(size_t)n * 256 + off] = bf16r(acc[af][nf][r] + bias);
        }
      }
    }
  }
}

// ---------------- level D: fill_csr + layer-1 gemm fused ----------------
// blocks [0, nbFill): CSR fill (random atomics + scatter, memory-bound).
// blocks [nbFill, ...): gemm4<D1> tiles (MFMA/LDS-bound). Complementary pipes.

template <int DIN>
__global__ __launch_bounds__(512) void fill_gemm1(
    const int* __restrict__ src, const int* __restrict__ dst,
    const int* __restrict__ rowptr, int* __restrict__ fill,
    int* __restrict__ csr_src, int E, int nbFill,
    const unsigned short* __restrict__ xb, int N,
    const unsigned short* __restrict__ Wt0, const float* __restrict__ B0,
    const unsigned short* __restrict__ Wt1, const float* __restrict__ B1,
    const unsigned short* __restrict__ Wt2, const float* __restrict__ B2,
    const unsigned short* __restrict__ Wt3, const float* __restrict__ B3,
    unsigned short* __restrict__ Qb, unsigned short* __restrict__ KV,
    float* __restrict__ Os) {
  int b = blockIdx.x;
  if (b < nbFill) {
    int e = b * 512 + threadIdx.x;
    if (e < E) {
      int d = dst[e];
      int pos = rowptr[d] + atomicAdd(&fill[d], 1);
      csr_src[pos] = src[e];
    }
    return;
  }
  int g = b - nbFill;
  gemm4_tile<DIN>(g >> 2, g & 3, threadIdx.x, xb, N, Wt0, B0, Wt1, B1,
                  Wt2, B2, Wt3, B3, Qb, KV, Os);
}

template <int DIN>
__global__ __launch_bounds__(512) void gemm4(
    const unsigned short* __restrict__ xb, int N,
    const unsigned short* __restrict__ Wt0, const float* __restrict__ B0,
    const unsigned short* __restrict__ Wt1, const float* __restrict__ B1,
    const unsigned short* __restrict__ Wt2, const float* __restrict__ B2,
    const unsigned short* __restrict__ Wt3, const float* __restrict__ B3,
    unsigned short* __restrict__ Qb, unsigned short* __restrict__ KV,
    float* __restrict__ Os) {
  gemm4_tile<DIN>(blockIdx.x, blockIdx.y, threadIdx.x, xb, N, Wt0, B0, Wt1, B1,
                  Wt2, B2, Wt3, B3, Qb, KV, Os);
}

// ---------------- edge aggregation ----------------
// One wave per dst node; 2 x 32-lane deferred-max online-softmax streams over
// alternating edges (prefetch depth 3), merged at end.
// kv slot l = {k[4l..4l+3], v[4l..4l+3]} bf16; q bf16 pre-scaled.

template <bool RELU, bool OUTBF16>
__global__ __launch_bounds__(256) void edge_agg2(
    const unsigned short* __restrict__ qb, const uint4* __restrict__ kv,
    const int* __restrict__ rowptr, const int* __restrict__ csr_src,
    const float* skip, void* outp, int N) {
  int tid = threadIdx.x;
  int lane = tid & 63;
  int wv = tid >> 6;
  int n = blockIdx.x * 4 + wv;
  if (n >= N) return;
  int g = lane >> 5;
  int l = lane & 31;
  uint2 qp = *(const uint2*)&qb[(size_t)n * 128 + 4 * l];
  float qx = __uint_as_float(qp.x << 16);
  float qy = __uint_as_float(qp.x & 0xffff0000u);
  float qz = __uint_as_float(qp.y << 16);
  float qw = __uint_as_float(qp.y & 0xffff0000u);
  int beg = rowptr[n];
  int deg = rowptr[n + 1] - beg;
  float m = -INFINITY, lsum = 0.f;
  float a0 = 0.f, a1 = 0.f, a2 = 0.f, a3 = 0.f;
  int cnt = (deg - g + 1) >> 1;
  const int* cp = csr_src + beg + g;
  uint4 kv0 = {0, 0, 0, 0}, kv1 = {0, 0, 0, 0}, kv2 = {0, 0, 0, 0};
  if (cnt >= 1) kv0 = kv[(size_t)cp[0] * 32 + l];
  if (cnt >= 2) kv1 = kv[(size_t)cp[2] * 32 + l];
  if (cnt >= 3) kv2 = kv[(size_t)cp[4] * 32 + l];
  for (int it = 0; it < cnt; ++it) {
    uint4 cur = kv0;
    kv0 = kv1;
    kv1 = kv2;
    if (it + 3 < cnt) kv2 = kv[(size_t)cp[2 * (it + 3)] * 32 + l];
    float k0 = __uint_as_float(cur.x << 16);
    float k1 = __uint_as_float(cur.x & 0xffff0000u);
    float k2 = __uint_as_float(cur.y << 16);
    float k3 = __uint_as_float(cur.y & 0xffff0000u);
    float d = qx * k0 + qy * k1 + qz * k2 + qw * k3;
#pragma unroll
    for (int off = 1; off < 32; off <<= 1) d += __shfl_xor(d, off);
    float v0 = __uint_as_float(cur.z << 16);
    float v1 = __uint_as_float(cur.z & 0xffff0000u);
    float v2 = __uint_as_float(cur.w << 16);
    float v3 = __uint_as_float(cur.w & 0xffff0000u);
    if (d > m + 8.f) {        // rare: new max beyond slack -> rescale
      float cf = __expf(m - d);
      lsum = lsum * cf + 1.f;
      a0 = a0 * cf + v0;
      a1 = a1 * cf + v1;
      a2 = a2 * cf + v2;
      a3 = a3 * cf + v3;
      m = d;
    } else {                  // common: accumulate against stale max
      float ef = __expf(d - m);
      lsum += ef;
      a0 += ef * v0;
      a1 += ef * v1;
      a2 += ef * v2;
      a3 += ef * v3;
    }
  }
  float m2 = __shfl_xor(m, 32);
  float L2 = __shfl_xor(lsum, 32);
  float b0 = __shfl_xor(a0, 32);
  float b1 = __shfl_xor(a1, 32);
  float b2 = __shfl_xor(a2, 32);
  float b3 = __shfl_xor(a3, 32);
  if (lane < 32) {
    float ox0 = 0.f, ox1 = 0.f, ox2 = 0.f, ox3 = 0.f;
    if (deg > 0) {
      float M = fmaxf(m, m2);
      float c1 = __expf(m - M);
      float c2 = __expf(m2 - M);
      float rl = 1.f / (lsum * c1 + L2 * c2 + 1e-16f);
      ox0 = (a0 * c1 + b0 * c2) * rl;
      ox1 = (a1 * c1 + b1 * c2) * rl;
      ox2 = (a2 * c1 + b2 * c2) * rl;
      ox3 = (a3 * c1 + b3 * c2) * rl;
    }
    const float* sp = skip + (size_t)n * 128 + 4 * l;
    float4 o = *(const float4*)sp;
    o.x += ox0; o.y += ox1; o.z += ox2; o.w += ox3;
    if (RELU) {
      o.x = fmaxf(o.x, 0.f);
      o.y = fmaxf(o.y, 0.f);
      o.z = fmaxf(o.z, 0.f);
      o.w = fmaxf(o.w, 0.f);
    }
    if (OUTBF16) {
      unsigned short* ob = (unsigned short*)outp + (size_t)n * 128 + 4 * l;
      uint2 pk;
      pk.x = pack_bf16_2(o.x, o.y);
      pk.y = pack_bf16_2(o.z, o.w);
      *(uint2*)ob = pk;
    } else {
      float* of = (float*)outp + (size_t)n * 128 + 4 * l;
      *(float4*)of = o;
    }
  }
}

// ---------------- global mean pool (batch sorted, bf16 input) ----------------

__global__ __launch_bounds__(128) void pool_kernel(const unsigned short* __restrict__ h,
                                                   const int* __restrict__ batch,
                                                   float* __restrict__ out, int N) {
  int g = blockIdx.x;
  int lo = 0, hi = N;
  while (lo < hi) { int mid = (lo + hi) >> 1; if (batch[mid] < g) lo = mid + 1; else hi = mid; }
  int s0 = lo;
  hi = N;
  while (lo < hi) { int mid = (lo + hi) >> 1; if (batch[mid] <= g) lo = mid + 1; else hi = mid; }
  int s1 = lo;
  int j = threadIdx.x;
  float acc = 0.f;
  for (int n = s0; n < s1; ++n) acc += bf16f(h[(size_t)n * 128 + j]);
  out[(size_t)g * 128 + j] = acc / fmaxf((float)(s1 - s0), 1.f);
}

// ---------------- launch ----------------

extern "C" void kernel_launch(void* const* d_in, const int* in_sizes, int n_in,
                              void* d_out, int out_size, void* d_ws, size_t ws_size,
                              hipStream_t stream) {
  const float* x = (const float*)d_in[0];
  const int* ei = (const int*)d_in[1];
  const int* batch = (const int*)d_in[2];
  const float* Wq1 = (const float*)d_in[3];
  const float* bq1 = (const float*)d_in[4];
  const float* Wk1 = (const float*)d_in[5];
  const float* bk1 = (const float*)d_in[6];
  const float* Wv1 = (const float*)d_in[7];
  const float* bv1 = (const float*)d_in[8];
  const float* Ws1 = (const float*)d_in[9];
  const float* bs1 = (const float*)d_in[10];
  const float* Wq2 = (const float*)d_in[11];
  const float* bq2 = (const float*)d_in[12];
  const float* Wk2 = (const float*)d_in[13];
  const float* bk2 = (const float*)d_in[14];
  const float* Wv2 = (const float*)d_in[15];
  const float* bv2 = (const float*)d_in[16];
  const float* Ws2 = (const float*)d_in[17];
  const float* bs2 = (const float*)d_in[18];

  int N = in_sizes[0] / D1;  // 50000
  int E = in_sizes[1] / 2;   // 800000
  int NG = out_size / DH;    // 512
  const int* src = ei;
  const int* dst = ei + E;

  char* ws = (char*)d_ws;
  unsigned short* qb = (unsigned short*)ws;  ws += (size_t)N * DH * 2;  // bf16 q (pre-scaled)
  unsigned short* kvb = (unsigned short*)ws; ws += (size_t)N * DH * 4;  // bf16 k|v interleaved
  float* s = (float*)ws;             ws += (size_t)N * DH * 4;   // skip
  unsigned short* h1b = (unsigned short*)ws; ws += (size_t)N * DH * 2;  // bf16 h1 / h2
  unsigned short* xb = (unsigned short*)ws;  ws += (size_t)N * D1 * 2;  // bf16 x
  unsigned short* wt[8];
  for (int m = 0; m < 8; ++m) {
    int din = (m < 4) ? 64 : 128;
    wt[m] = (unsigned short*)ws;
    ws += (size_t)128 * din * 2;
  }
  ws = (char*)(((size_t)ws + 255) & ~(size_t)255);
  int* rowptr = (int*)ws; ws += (size_t)(N + 1) * 4;
  ws = (char*)(((size_t)ws + 255) & ~(size_t)255);
  int* deg = (int*)ws;  ws += (size_t)N * 4;
  int* fill = (int*)ws; ws += (size_t)N * 4;   // contiguous with deg: one memset
  int* incl = (int*)ws; ws += (size_t)N * 4;
  int* sums = (int*)ws; ws += 1024;
  int* csr = (int*)ws;  ws += (size_t)E * 4;

  int nch = (N + SCHUNK - 1) / SCHUNK;
  int nbHist = ((E >> 2) + 255) / 256;
  int nb = (N + 127) / 128;
  int nbFill = (E + 511) / 512;

  hipMemsetAsync(deg, 0, (size_t)2 * N * 4, stream);  // deg + fill

  // level A: histogram + weight/x prep (independent, one dispatch)
  hist_prep<<<nbHist + 768, 256, 0, stream>>>(
      dst, deg, E, nbHist, Wq1, Wk1, Wv1, Ws1, Wq2, Wk2, Wv2, Ws2,
      wt[0], wt[1], wt[2], wt[3], wt[4], wt[5], wt[6], wt[7],
      (const float4*)x, (uint2*)xb, N * D1 / 4);
  scan_chunks<<<nch, 256, 0, stream>>>(deg, incl, sums, N);
  finalize_rowptr<<<(N + 255) / 256, 256, 0, stream>>>(incl, sums, rowptr, N);
  // level D: CSR fill + layer-1 gemm overlapped in one dispatch
  fill_gemm1<D1><<<nbFill + nb * 4, 512, 0, stream>>>(
      src, dst, rowptr, fill, csr, E, nbFill, xb, N,
      wt[0], bq1, wt[1], bk1, wt[2], bv1, wt[3], bs1, qb, kvb, s);
  edge_agg2<true, true><<<(N + 3) / 4, 256, 0, stream>>>(
      qb, (const uint4*)kvb, rowptr, csr, s, h1b, N);
  // layer 2
  gemm4<DH><<<dim3(nb, 4), 512, 0, stream>>>(h1b, N, wt[4], bq2, wt[5], bk2,
                                             wt[6], bv2, wt[7], bs2, qb, kvb, s);
  edge_agg2<false, true><<<(N + 3) / 4, 256, 0, stream>>>(
      qb, (const uint4*)kvb, rowptr, csr, s, h1b, N);
  // mean pool (bf16 input)
  pool_kernel<<<NG, 128, 0, stream>>>(h1b, batch, (float*)d_out, N);
}

// Round 12
// 275.540 us; speedup vs baseline: 1.3717x; 1.2228x over previous
//
#include <hip/hip_runtime.h>
#include <hip/hip_fp8.h>
#include <math.h>

// DrugEncoder: 2x TransformerConv (heads=1) + global mean pool.
// N=50000 nodes, E=800000 edges, G=512 graphs, D_IN=64, D_HID=D_EMB=128.
//
// R12: atomic-free CSR fill (ranks from hist), interleaved fill/gemm blocks,
//      kv row = [k fp8 e4m3 128B | v bf16 256B] (384B gather, single-block
//      line ownership). q bf16 pre-scaled; skip fp32; h1/h2 bf16.

constexpr int D1 = 64;
constexpr int DH = 128;
constexpr int SCHUNK = 1024;
constexpr float QSCALE = 0.08838834764831845f;  // 1/sqrt(128)

typedef __attribute__((ext_vector_type(8))) short short8v;
typedef __attribute__((ext_vector_type(4))) float f32x4;

__device__ inline unsigned short bf16r(float f) {
  unsigned u = __float_as_uint(f);
  return (unsigned short)((u + 0x7fffu + ((u >> 16) & 1u)) >> 16);
}

__device__ inline unsigned pack_bf16_2(float a, float b) {
  return (unsigned)bf16r(a) | ((unsigned)bf16r(b) << 16);
}

__device__ inline float bf16f(unsigned short u) {
  return __uint_as_float(((unsigned)u) << 16);
}

__device__ inline float fp8f(unsigned b) {
  __hip_fp8_e4m3 h;
  h.__x = (unsigned char)b;
  return (float)h;
}

__device__ inline unsigned char fp8e(float f) {
  __hip_fp8_e4m3 h(f);
  return h.__x;
}

// ---------------- level A: histogram(+ranks) + weight/x prep ----------------
// blocks [0, nbHist): dst histogram, 4 edges/thread via int4; rank[e] saved.
// blocks [nbHist, nbHist+512): W transpose+bf16. [.., +768): x -> bf16.

__global__ __launch_bounds__(256) void hist_prep(
    const int* __restrict__ dst, int* __restrict__ deg, int* __restrict__ rank,
    int E, int nbHist,
    const float* w0, const float* w1, const float* w2, const float* w3,
    const float* w4, const float* w5, const float* w6, const float* w7,
    unsigned short* t0, unsigned short* t1, unsigned short* t2,
    unsigned short* t3, unsigned short* t4, unsigned short* t5,
    unsigned short* t6, unsigned short* t7,
    const float4* __restrict__ x, uint2* __restrict__ xb, int n4) {
  int b = blockIdx.x;
  int tid = threadIdx.x;
  if (b < nbHist) {
    int i = b * 256 + tid;
    if (i < (E >> 2)) {
      int4 d4 = ((const int4*)dst)[i];
      int4 r4;
      r4.x = atomicAdd(&deg[d4.x], 1);
      r4.y = atomicAdd(&deg[d4.y], 1);
      r4.z = atomicAdd(&deg[d4.z], 1);
      r4.w = atomicAdd(&deg[d4.w], 1);
      ((int4*)rank)[i] = r4;
    }
    if (b == 0 && tid == 0) {
      for (int e = E & ~3; e < E; ++e) rank[e] = atomicAdd(&deg[dst[e]], 1);
    }
    return;
  }
  int g = b - nbHist;
  if (g < 512) {
    int m = g >> 6, bx = g & 63;
    const float* W;
    unsigned short* T;
    switch (m) {
      case 0: W = w0; T = t0; break;
      case 1: W = w1; T = t1; break;
      case 2: W = w2; T = t2; break;
      case 3: W = w3; T = t3; break;
      case 4: W = w4; T = t4; break;
      case 5: W = w5; T = t5; break;
      case 6: W = w6; T = t6; break;
      default: W = w7; T = t7; break;
    }
    int din = (m < 4) ? 64 : 128;
    int total = din * 128;
    int i = bx * 256 + tid;
    if (i < total) {
      int r = i >> 7, c = i & 127;  // W[r][c]
      T[c * din + r] = bf16r(W[i]);
    }
    return;
  }
  int bx = g - 512;  // 256 blocks
  for (int i = bx * 256 + tid; i < n4; i += 256 * 256) {
    float4 v = x[i];
    uint2 o;
    o.x = pack_bf16_2(v.x, v.y);
    o.y = pack_bf16_2(v.z, v.w);
    xb[i] = o;
  }
}

// ---------------- CSR scan ----------------

__global__ void scan_chunks(const int* __restrict__ deg, int* __restrict__ incl,
                            int* __restrict__ sums, int N) {
  __shared__ int lds[256];
  int b = blockIdx.x, tid = threadIdx.x;
  int base = b * SCHUNK + tid * 4;
  int e0 = (base + 0 < N) ? deg[base + 0] : 0;
  int e1 = (base + 1 < N) ? deg[base + 1] : 0;
  int e2 = (base + 2 < N) ? deg[base + 2] : 0;
  int e3 = (base + 3 < N) ? deg[base + 3] : 0;
  int t0 = e0, t1 = t0 + e1, t2 = t1 + e2, t3 = t2 + e3;
  lds[tid] = t3;
  __syncthreads();
  for (int off = 1; off < 256; off <<= 1) {
    int v = (tid >= off) ? lds[tid - off] : 0;
    __syncthreads();
    lds[tid] += v;
    __syncthreads();
  }
  int excl = (tid > 0) ? lds[tid - 1] : 0;
  if (base + 0 < N) incl[base + 0] = t0 + excl;
  if (base + 1 < N) incl[base + 1] = t1 + excl;
  if (base + 2 < N) incl[base + 2] = t2 + excl;
  if (base + 3 < N) incl[base + 3] = t3 + excl;
  if (tid == 255) sums[b] = lds[255];
}

__global__ void finalize_rowptr(const int* __restrict__ incl, const int* __restrict__ sums,
                                int* __restrict__ rowptr, int N) {
  int n = blockIdx.x * blockDim.x + threadIdx.x;
  if (n < N) {
    int ch = n / SCHUNK;
    int off = 0;
    for (int i = 0; i < ch; ++i) off += sums[i];
    rowptr[n + 1] = incl[n] + off;
  }
  if (n == 0) rowptr[0] = 0;
}

// ---------------- bf16 MFMA 4-way linear (tile body) ----------------
// y: 0=q(bf16 pre-scaled) 1=k(fp8 -> kv[0..128)) 2=v(bf16 -> kv[128..384))
// 3=skip(fp32). 512 threads = 8 waves, 2x4: wave owns 64 rows x 32 cols.

template <int DIN>
__device__ __forceinline__ void gemm4_tile(
    int bx, int y, int tid,
    const unsigned short* __restrict__ xb, int N,
    const unsigned short* __restrict__ Wt0, const float* __restrict__ B0,
    const unsigned short* __restrict__ Wt1, const float* __restrict__ B1,
    const unsigned short* __restrict__ Wt2, const float* __restrict__ B2,
    const unsigned short* __restrict__ Wt3, const float* __restrict__ B3,
    unsigned short* __restrict__ Qb, unsigned char* __restrict__ KV,
    float* __restrict__ Os) {
  constexpr int DS = DIN + 8;
  __shared__ __align__(16) unsigned short As[128 * DS];
  __shared__ __align__(16) unsigned short Bs[128 * DS];
  const unsigned short* Wt;
  const float* Bias;
  switch (y) {
    case 0: Wt = Wt0; Bias = B0; break;
    case 1: Wt = Wt1; Bias = B1; break;
    case 2: Wt = Wt2; Bias = B2; break;
    default: Wt = Wt3; Bias = B3; break;
  }
  int n0 = bx * 128;

  constexpr int CPR = DIN / 8;
  constexpr int ACH = 128 * CPR;
#pragma unroll
  for (int c = tid; c < ACH; c += 512) {
    int row = c / CPR, c8 = c - row * CPR;
    int n = n0 + row;
    uint4 val = {0u, 0u, 0u, 0u};
    if (n < N) val = *(const uint4*)&xb[(size_t)n * DIN + c8 * 8];
    *(uint4*)&As[row * DS + c8 * 8] = val;
  }
#pragma unroll
  for (int c = tid; c < ACH; c += 512) {
    int row = c / CPR, c8 = c - row * CPR;
    uint4 val = *(const uint4*)&Wt[(size_t)row * DIN + c8 * 8];
    *(uint4*)&Bs[row * DS + c8 * 8] = val;
  }
  __syncthreads();

  int w = tid >> 6, lane = tid & 63, lr = lane & 15, lg = lane >> 4;
  int wr = w >> 2;
  int wc = w & 3;
  constexpr int KS = DIN / 32;

  short8v a[4][KS];
#pragma unroll
  for (int af = 0; af < 4; ++af)
#pragma unroll
    for (int ks = 0; ks < KS; ++ks)
      a[af][ks] = *(const short8v*)&As[(wr * 64 + af * 16 + lr) * DS + ks * 32 + lg * 8];

  f32x4 acc[4][2];
#pragma unroll
  for (int af = 0; af < 4; ++af)
#pragma unroll
    for (int nf = 0; nf < 2; ++nf) acc[af][nf] = (f32x4){0.f, 0.f, 0.f, 0.f};

#pragma unroll
  for (int ks = 0; ks < KS; ++ks) {
#pragma unroll
    for (int nf = 0; nf < 2; ++nf) {
      short8v b = *(const short8v*)&Bs[(wc * 32 + nf * 16 + lr) * DS + ks * 32 + lg * 8];
#pragma unroll
      for (int af = 0; af < 4; ++af)
        acc[af][nf] = __builtin_amdgcn_mfma_f32_16x16x32_bf16(a[af][ks], b, acc[af][nf], 0, 0, 0);
    }
  }

#pragma unroll
  for (int af = 0; af < 4; ++af) {
    int rbase = n0 + wr * 64 + af * 16 + lg * 4;
#pragma unroll
    for (int nf = 0; nf < 2; ++nf) {
      int col = wc * 32 + nf * 16 + lr;
      float bias = Bias[col];
      if (y == 0) {
#pragma unroll
        for (int r = 0; r < 4; ++r) {
          int n = rbase + r;
          if (n < N) Qb[(size_t)n * 128 + col] = bf16r((acc[af][nf][r] + bias) * QSCALE);
        }
      } else if (y == 1) {
#pragma unroll
        for (int r = 0; r < 4; ++r) {
          int n = rbase + r;
          if (n < N) KV[(size_t)n * 384 + col] = fp8e(acc[af][nf][r] + bias);
        }
      } else if (y == 2) {
#pragma unroll
        for (int r = 0; r < 4; ++r) {
          int n = rbase + r;
          if (n < N)
            *(unsigned short*)&KV[(size_t)n * 384 + 128 + col * 2] =
                bf16r(acc[af][nf][r] + bias);
        }
      } else {
#pragma unroll
        for (int r = 0; r < 4; ++r) {
          int n = rbase + r;
          if (n < N) Os[(size_t)n * 128 + col] = acc[af][nf][r] + bias;
        }
      }
    }
  }
}

// ---------------- level D: fill_csr + layer-1 gemm, interleaved ----------------
// b%5==0 -> fill block (atomic-free, ranks precomputed); else gemm tile.

template <int DIN>
__global__ __launch_bounds__(512) void fill_gemm1(
    const int* __restrict__ src, const int* __restrict__ dst,
    const int* __restrict__ rank, const int* __restrict__ rowptr,
    int* __restrict__ csr_src, int E, int epb4,
    const unsigned short* __restrict__ xb, int N,
    const unsigned short* __restrict__ Wt0, const float* __restrict__ B0,
    const unsigned short* __restrict__ Wt1, const float* __restrict__ B1,
    const unsigned short* __restrict__ Wt2, const float* __restrict__ B2,
    const unsigned short* __restrict__ Wt3, const float* __restrict__ B3,
    unsigned short* __restrict__ Qb, unsigned char* __restrict__ KV,
    float* __restrict__ Os) {
  int b = blockIdx.x;
  int b5 = b / 5, r5 = b - b5 * 5;
  if (r5 == 0) {
    int e4 = E >> 2;
    int end = min((b5 + 1) * epb4, e4);
    for (int i = b5 * epb4 + threadIdx.x; i < end; i += 512) {
      int4 d4 = ((const int4*)dst)[i];
      int4 r4 = ((const int4*)rank)[i];
      int4 s4 = ((const int4*)src)[i];
      csr_src[rowptr[d4.x] + r4.x] = s4.x;
      csr_src[rowptr[d4.y] + r4.y] = s4.y;
      csr_src[rowptr[d4.z] + r4.z] = s4.z;
      csr_src[rowptr[d4.w] + r4.w] = s4.w;
    }
    if (b5 == 0 && threadIdx.x == 0) {
      for (int e = E & ~3; e < E; ++e) csr_src[rowptr[dst[e]] + rank[e]] = src[e];
    }
    return;
  }
  int g = b5 * 4 + r5 - 1;
  gemm4_tile<DIN>(g >> 2, g & 3, threadIdx.x, xb, N, Wt0, B0, Wt1, B1,
                  Wt2, B2, Wt3, B3, Qb, KV, Os);
}

template <int DIN>
__global__ __launch_bounds__(512) void gemm4(
    const unsigned short* __restrict__ xb, int N,
    const unsigned short* __restrict__ Wt0, const float* __restrict__ B0,
    const unsigned short* __restrict__ Wt1, const float* __restrict__ B1,
    const unsigned short* __restrict__ Wt2, const float* __restrict__ B2,
    const unsigned short* __restrict__ Wt3, const float* __restrict__ B3,
    unsigned short* __restrict__ Qb, unsigned char* __restrict__ KV,
    float* __restrict__ Os) {
  gemm4_tile<DIN>(blockIdx.x, blockIdx.y, threadIdx.x, xb, N, Wt0, B0, Wt1, B1,
                  Wt2, B2, Wt3, B3, Qb, KV, Os);
}

// ---------------- edge aggregation ----------------
// One wave per dst node; 2 x 32-lane deferred-max online-softmax streams over
// alternating edges (prefetch depth 3). kv row: k fp8 [0,128), v bf16 [128,384).

template <bool RELU, bool OUTBF16>
__global__ __launch_bounds__(256) void edge_agg2(
    const unsigned short* __restrict__ qb, const unsigned char* __restrict__ kv,
    const int* __restrict__ rowptr, const int* __restrict__ csr_src,
    const float* skip, void* outp, int N) {
  int tid = threadIdx.x;
  int lane = tid & 63;
  int wv = tid >> 6;
  int n = blockIdx.x * 4 + wv;
  if (n >= N) return;
  int g = lane >> 5;
  int l = lane & 31;
  uint2 qp = *(const uint2*)&qb[(size_t)n * 128 + 4 * l];
  float qx = __uint_as_float(qp.x << 16);
  float qy = __uint_as_float(qp.x & 0xffff0000u);
  float qz = __uint_as_float(qp.y << 16);
  float qw = __uint_as_float(qp.y & 0xffff0000u);
  int beg = rowptr[n];
  int deg = rowptr[n + 1] - beg;
  float m = -INFINITY, lsum = 0.f;
  float a0 = 0.f, a1 = 0.f, a2 = 0.f, a3 = 0.f;
  int cnt = (deg - g + 1) >> 1;
  const int* cp = csr_src + beg + g;
  unsigned kw0 = 0, kw1 = 0, kw2 = 0;
  uint2 vw0 = {0, 0}, vw1 = {0, 0}, vw2 = {0, 0};
  if (cnt >= 1) {
    size_t r = (size_t)cp[0] * 384;
    kw0 = *(const unsigned*)(kv + r + 4 * l);
    vw0 = *(const uint2*)(kv + r + 128 + 8 * l);
  }
  if (cnt >= 2) {
    size_t r = (size_t)cp[2] * 384;
    kw1 = *(const unsigned*)(kv + r + 4 * l);
    vw1 = *(const uint2*)(kv + r + 128 + 8 * l);
  }
  if (cnt >= 3) {
    size_t r = (size_t)cp[4] * 384;
    kw2 = *(const unsigned*)(kv + r + 4 * l);
    vw2 = *(const uint2*)(kv + r + 128 + 8 * l);
  }
  for (int it = 0; it < cnt; ++it) {
    unsigned kc = kw0;
    uint2 vc = vw0;
    kw0 = kw1; kw1 = kw2;
    vw0 = vw1; vw1 = vw2;
    if (it + 3 < cnt) {
      size_t r = (size_t)cp[2 * (it + 3)] * 384;
      kw2 = *(const unsigned*)(kv + r + 4 * l);
      vw2 = *(const uint2*)(kv + r + 128 + 8 * l);
    }
    float k0 = fp8f(kc & 0xffu);
    float k1 = fp8f((kc >> 8) & 0xffu);
    float k2 = fp8f((kc >> 16) & 0xffu);
    float k3 = fp8f(kc >> 24);
    float d = qx * k0 + qy * k1 + qz * k2 + qw * k3;
#pragma unroll
    for (int off = 1; off < 32; off <<= 1) d += __shfl_xor(d, off);
    float v0 = __uint_as_float(vc.x << 16);
    float v1 = __uint_as_float(vc.x & 0xffff0000u);
    float v2 = __uint_as_float(vc.y << 16);
    float v3 = __uint_as_float(vc.y & 0xffff0000u);
    if (d > m + 8.f) {        // rare: new max beyond slack -> rescale
      float cf = __expf(m - d);
      lsum = lsum * cf + 1.f;
      a0 = a0 * cf + v0;
      a1 = a1 * cf + v1;
      a2 = a2 * cf + v2;
      a3 = a3 * cf + v3;
      m = d;
    } else {                  // common: accumulate against stale max
      float ef = __expf(d - m);
      lsum += ef;
      a0 += ef * v0;
      a1 += ef * v1;
      a2 += ef * v2;
      a3 += ef * v3;
    }
  }
  float m2 = __shfl_xor(m, 32);
  float L2 = __shfl_xor(lsum, 32);
  float b0 = __shfl_xor(a0, 32);
  float b1 = __shfl_xor(a1, 32);
  float b2 = __shfl_xor(a2, 32);
  float b3 = __shfl_xor(a3, 32);
  if (lane < 32) {
    float ox0 = 0.f, ox1 = 0.f, ox2 = 0.f, ox3 = 0.f;
    if (deg > 0) {
      float M = fmaxf(m, m2);
      float c1 = __expf(m - M);
      float c2 = __expf(m2 - M);
      float rl = 1.f / (lsum * c1 + L2 * c2 + 1e-16f);
      ox0 = (a0 * c1 + b0 * c2) * rl;
      ox1 = (a1 * c1 + b1 * c2) * rl;
      ox2 = (a2 * c1 + b2 * c2) * rl;
      ox3 = (a3 * c1 + b3 * c2) * rl;
    }
    const float* sp = skip + (size_t)n * 128 + 4 * l;
    float4 o = *(const float4*)sp;
    o.x += ox0; o.y += ox1; o.z += ox2; o.w += ox3;
    if (RELU) {
      o.x = fmaxf(o.x, 0.f);
      o.y = fmaxf(o.y, 0.f);
      o.z = fmaxf(o.z, 0.f);
      o.w = fmaxf(o.w, 0.f);
    }
    if (OUTBF16) {
      unsigned short* ob = (unsigned short*)outp + (size_t)n * 128 + 4 * l;
      uint2 pk;
      pk.x = pack_bf16_2(o.x, o.y);
      pk.y = pack_bf16_2(o.z, o.w);
      *(uint2*)ob = pk;
    } else {
      float* of = (float*)outp + (size_t)n * 128 + 4 * l;
      *(float4*)of = o;
    }
  }
}

// ---------------- global mean pool (batch sorted, bf16 input) ----------------

__global__ __launch_bounds__(128) void pool_kernel(const unsigned short* __restrict__ h,
                                                   const int* __restrict__ batch,
                                                   float* __restrict__ out, int N) {
  int g = blockIdx.x;
  int lo = 0, hi = N;
  while (lo < hi) { int mid = (lo + hi) >> 1; if (batch[mid] < g) lo = mid + 1; else hi = mid; }
  int s0 = lo;
  hi = N;
  while (lo < hi) { int mid = (lo + hi) >> 1; if (batch[mid] <= g) lo = mid + 1; else hi = mid; }
  int s1 = lo;
  int j = threadIdx.x;
  float acc = 0.f;
  for (int n = s0; n < s1; ++n) acc += bf16f(h[(size_t)n * 128 + j]);
  out[(size_t)g * 128 + j] = acc / fmaxf((float)(s1 - s0), 1.f);
}

// ---------------- launch ----------------

extern "C" void kernel_launch(void* const* d_in, const int* in_sizes, int n_in,
                              void* d_out, int out_size, void* d_ws, size_t ws_size,
                              hipStream_t stream) {
  const float* x = (const float*)d_in[0];
  const int* ei = (const int*)d_in[1];
  const int* batch = (const int*)d_in[2];
  const float* Wq1 = (const float*)d_in[3];
  const float* bq1 = (const float*)d_in[4];
  const float* Wk1 = (const float*)d_in[5];
  const float* bk1 = (const float*)d_in[6];
  const float* Wv1 = (const float*)d_in[7];
  const float* bv1 = (const float*)d_in[8];
  const float* Ws1 = (const float*)d_in[9];
  const float* bs1 = (const float*)d_in[10];
  const float* Wq2 = (const float*)d_in[11];
  const float* bq2 = (const float*)d_in[12];
  const float* Wk2 = (const float*)d_in[13];
  const float* bk2 = (const float*)d_in[14];
  const float* Wv2 = (const float*)d_in[15];
  const float* bv2 = (const float*)d_in[16];
  const float* Ws2 = (const float*)d_in[17];
  const float* bs2 = (const float*)d_in[18];

  int N = in_sizes[0] / D1;  // 50000
  int E = in_sizes[1] / 2;   // 800000
  int NG = out_size / DH;    // 512
  const int* src = ei;
  const int* dst = ei + E;

  char* ws = (char*)d_ws;
  unsigned short* qb = (unsigned short*)ws;  ws += (size_t)N * DH * 2;   // bf16 q (pre-scaled)
  unsigned char* kvb = (unsigned char*)ws;   ws += (size_t)N * 384;     // k fp8 | v bf16
  ws = (char*)(((size_t)ws + 255) & ~(size_t)255);
  float* s = (float*)ws;             ws += (size_t)N * DH * 4;   // skip
  unsigned short* h1b = (unsigned short*)ws; ws += (size_t)N * DH * 2;  // bf16 h1 / h2
  unsigned short* xb = (unsigned short*)ws;  ws += (size_t)N * D1 * 2;  // bf16 x
  unsigned short* wt[8];
  for (int m = 0; m < 8; ++m) {
    int din = (m < 4) ? 64 : 128;
    wt[m] = (unsigned short*)ws;
    ws += (size_t)128 * din * 2;
  }
  ws = (char*)(((size_t)ws + 255) & ~(size_t)255);
  int* rowptr = (int*)ws; ws += (size_t)(N + 1) * 4;
  ws = (char*)(((size_t)ws + 255) & ~(size_t)255);
  int* deg = (int*)ws;  ws += (size_t)N * 4;
  int* incl = (int*)ws; ws += (size_t)N * 4;
  int* sums = (int*)ws; ws += 1024;
  int* rank = (int*)ws; ws += (size_t)E * 4;
  int* csr = (int*)ws;  ws += (size_t)E * 4;

  int nch = (N + SCHUNK - 1) / SCHUNK;
  int nbHist = ((E >> 2) + 255) / 256;
  int nb = (N + 127) / 128;           // 391 gemm tiles (x4 y)
  int epb4 = ((E >> 2) + nb - 1) / nb;  // int4 edges per fill block

  hipMemsetAsync(deg, 0, (size_t)N * 4, stream);

  // level A: histogram+ranks + weight/x prep (one dispatch)
  hist_prep<<<nbHist + 768, 256, 0, stream>>>(
      dst, deg, rank, E, nbHist, Wq1, Wk1, Wv1, Ws1, Wq2, Wk2, Wv2, Ws2,
      wt[0], wt[1], wt[2], wt[3], wt[4], wt[5], wt[6], wt[7],
      (const float4*)x, (uint2*)xb, N * D1 / 4);
  scan_chunks<<<nch, 256, 0, stream>>>(deg, incl, sums, N);
  finalize_rowptr<<<(N + 255) / 256, 256, 0, stream>>>(incl, sums, rowptr, N);
  // level D: CSR fill + layer-1 gemm, block-interleaved 1:4
  fill_gemm1<D1><<<nb * 5, 512, 0, stream>>>(
      src, dst, rank, rowptr, csr, E, epb4, xb, N,
      wt[0], bq1, wt[1], bk1, wt[2], bv1, wt[3], bs1, qb, kvb, s);
  edge_agg2<true, true><<<(N + 3) / 4, 256, 0, stream>>>(
      qb, kvb, rowptr, csr, s, h1b, N);
  // layer 2
  gemm4<DH><<<dim3(nb, 4), 512, 0, stream>>>(h1b, N, wt[4], bq2, wt[5], bk2,
                                             wt[6], bv2, wt[7], bs2, qb, kvb, s);
  edge_agg2<false, true><<<(N + 3) / 4, 256, 0, stream>>>(
      qb, kvb, rowptr, csr, s, h1b, N);
  // mean pool (bf16 input)
  pool_kernel<<<NG, 128, 0, stream>>>(h1b, batch, (float*)d_out, N);
}

// Round 13
// 258.565 us; speedup vs baseline: 1.4617x; 1.0657x over previous
//
#include <hip/hip_runtime.h>
#include <hip/hip_fp8.h>
#include <math.h>

// DrugEncoder: 2x TransformerConv (heads=1) + global mean pool.
// N=50000 nodes, E=800000 edges, G=512 graphs, D_IN=64, D_HID=D_EMB=128.
//
// R13: edge_agg -> 4 x 16-lane streams (8 dims/lane): 4-level shfl reduce,
//      half the wave-iterations, HW fp8 decode (cvt_pk_f32_fp8).
//      Rest unchanged from R12 (atomic-free fill + interleaved gemm1, fp8 k /
//      bf16 v 384B kv rows, bf16 h1/h2 + bf16 pool).

constexpr int D1 = 64;
constexpr int DH = 128;
constexpr int SCHUNK = 1024;
constexpr float QSCALE = 0.08838834764831845f;  // 1/sqrt(128)

typedef __attribute__((ext_vector_type(8))) short short8v;
typedef __attribute__((ext_vector_type(4))) float f32x4;
typedef __attribute__((ext_vector_type(2))) float f32x2;

#if __has_builtin(__builtin_amdgcn_cvt_pk_f32_fp8)
#define HW_FP8_DEC 1
#endif

__device__ inline unsigned short bf16r(float f) {
  unsigned u = __float_as_uint(f);
  return (unsigned short)((u + 0x7fffu + ((u >> 16) & 1u)) >> 16);
}

__device__ inline unsigned pack_bf16_2(float a, float b) {
  return (unsigned)bf16r(a) | ((unsigned)bf16r(b) << 16);
}

__device__ inline float bf16f(unsigned short u) {
  return __uint_as_float(((unsigned)u) << 16);
}

__device__ inline unsigned char fp8e(float f) {
  __hip_fp8_e4m3 h(f);
  return h.__x;
}

#ifndef HW_FP8_DEC
__device__ inline float fp8f_sw(unsigned b) {
  unsigned e = (b >> 3) & 15u, mm = b & 7u;
  float v;
  if (e == 0) v = (float)mm * 0.001953125f;  // m * 2^-9
  else v = __uint_as_float(((e + 119u) << 23) | (mm << 20));
  return (b & 0x80u) ? -v : v;
}
#endif

// ---------------- level A: histogram(+ranks) + weight/x prep ----------------

__global__ __launch_bounds__(256) void hist_prep(
    const int* __restrict__ dst, int* __restrict__ deg, int* __restrict__ rank,
    int E, int nbHist,
    const float* w0, const float* w1, const float* w2, const float* w3,
    const float* w4, const float* w5, const float* w6, const float* w7,
    unsigned short* t0, unsigned short* t1, unsigned short* t2,
    unsigned short* t3, unsigned short* t4, unsigned short* t5,
    unsigned short* t6, unsigned short* t7,
    const float4* __restrict__ x, uint2* __restrict__ xb, int n4) {
  int b = blockIdx.x;
  int tid = threadIdx.x;
  if (b < nbHist) {
    int i = b * 256 + tid;
    if (i < (E >> 2)) {
      int4 d4 = ((const int4*)dst)[i];
      int4 r4;
      r4.x = atomicAdd(&deg[d4.x], 1);
      r4.y = atomicAdd(&deg[d4.y], 1);
      r4.z = atomicAdd(&deg[d4.z], 1);
      r4.w = atomicAdd(&deg[d4.w], 1);
      ((int4*)rank)[i] = r4;
    }
    if (b == 0 && tid == 0) {
      for (int e = E & ~3; e < E; ++e) rank[e] = atomicAdd(&deg[dst[e]], 1);
    }
    return;
  }
  int g = b - nbHist;
  if (g < 512) {
    int m = g >> 6, bx = g & 63;
    const float* W;
    unsigned short* T;
    switch (m) {
      case 0: W = w0; T = t0; break;
      case 1: W = w1; T = t1; break;
      case 2: W = w2; T = t2; break;
      case 3: W = w3; T = t3; break;
      case 4: W = w4; T = t4; break;
      case 5: W = w5; T = t5; break;
      case 6: W = w6; T = t6; break;
      default: W = w7; T = t7; break;
    }
    int din = (m < 4) ? 64 : 128;
    int total = din * 128;
    int i = bx * 256 + tid;
    if (i < total) {
      int r = i >> 7, c = i & 127;  // W[r][c]
      T[c * din + r] = bf16r(W[i]);
    }
    return;
  }
  int bx = g - 512;  // 256 blocks
  for (int i = bx * 256 + tid; i < n4; i += 256 * 256) {
    float4 v = x[i];
    uint2 o;
    o.x = pack_bf16_2(v.x, v.y);
    o.y = pack_bf16_2(v.z, v.w);
    xb[i] = o;
  }
}

// ---------------- CSR scan ----------------

__global__ void scan_chunks(const int* __restrict__ deg, int* __restrict__ incl,
                            int* __restrict__ sums, int N) {
  __shared__ int lds[256];
  int b = blockIdx.x, tid = threadIdx.x;
  int base = b * SCHUNK + tid * 4;
  int e0 = (base + 0 < N) ? deg[base + 0] : 0;
  int e1 = (base + 1 < N) ? deg[base + 1] : 0;
  int e2 = (base + 2 < N) ? deg[base + 2] : 0;
  int e3 = (base + 3 < N) ? deg[base + 3] : 0;
  int t0 = e0, t1 = t0 + e1, t2 = t1 + e2, t3 = t2 + e3;
  lds[tid] = t3;
  __syncthreads();
  for (int off = 1; off < 256; off <<= 1) {
    int v = (tid >= off) ? lds[tid - off] : 0;
    __syncthreads();
    lds[tid] += v;
    __syncthreads();
  }
  int excl = (tid > 0) ? lds[tid - 1] : 0;
  if (base + 0 < N) incl[base + 0] = t0 + excl;
  if (base + 1 < N) incl[base + 1] = t1 + excl;
  if (base + 2 < N) incl[base + 2] = t2 + excl;
  if (base + 3 < N) incl[base + 3] = t3 + excl;
  if (tid == 255) sums[b] = lds[255];
}

__global__ void finalize_rowptr(const int* __restrict__ incl, const int* __restrict__ sums,
                                int* __restrict__ rowptr, int N) {
  int n = blockIdx.x * blockDim.x + threadIdx.x;
  if (n < N) {
    int ch = n / SCHUNK;
    int off = 0;
    for (int i = 0; i < ch; ++i) off += sums[i];
    rowptr[n + 1] = incl[n] + off;
  }
  if (n == 0) rowptr[0] = 0;
}

// ---------------- bf16 MFMA 4-way linear (tile body) ----------------
// y: 0=q(bf16 pre-scaled) 1=k(fp8 -> kv[0..128)) 2=v(bf16 -> kv[128..384))
// 3=skip(fp32). 512 threads = 8 waves, 2x4: wave owns 64 rows x 32 cols.

template <int DIN>
__device__ __forceinline__ void gemm4_tile(
    int bx, int y, int tid,
    const unsigned short* __restrict__ xb, int N,
    const unsigned short* __restrict__ Wt0, const float* __restrict__ B0,
    const unsigned short* __restrict__ Wt1, const float* __restrict__ B1,
    const unsigned short* __restrict__ Wt2, const float* __restrict__ B2,
    const unsigned short* __restrict__ Wt3, const float* __restrict__ B3,
    unsigned short* __restrict__ Qb, unsigned char* __restrict__ KV,
    float* __restrict__ Os) {
  constexpr int DS = DIN + 8;
  __shared__ __align__(16) unsigned short As[128 * DS];
  __shared__ __align__(16) unsigned short Bs[128 * DS];
  const unsigned short* Wt;
  const float* Bias;
  switch (y) {
    case 0: Wt = Wt0; Bias = B0; break;
    case 1: Wt = Wt1; Bias = B1; break;
    case 2: Wt = Wt2; Bias = B2; break;
    default: Wt = Wt3; Bias = B3; break;
  }
  int n0 = bx * 128;

  constexpr int CPR = DIN / 8;
  constexpr int ACH = 128 * CPR;
#pragma unroll
  for (int c = tid; c < ACH; c += 512) {
    int row = c / CPR, c8 = c - row * CPR;
    int n = n0 + row;
    uint4 val = {0u, 0u, 0u, 0u};
    if (n < N) val = *(const uint4*)&xb[(size_t)n * DIN + c8 * 8];
    *(uint4*)&As[row * DS + c8 * 8] = val;
  }
#pragma unroll
  for (int c = tid; c < ACH; c += 512) {
    int row = c / CPR, c8 = c - row * CPR;
    uint4 val = *(const uint4*)&Wt[(size_t)row * DIN + c8 * 8];
    *(uint4*)&Bs[row * DS + c8 * 8] = val;
  }
  __syncthreads();

  int w = tid >> 6, lane = tid & 63, lr = lane & 15, lg = lane >> 4;
  int wr = w >> 2;
  int wc = w & 3;
  constexpr int KS = DIN / 32;

  short8v a[4][KS];
#pragma unroll
  for (int af = 0; af < 4; ++af)
#pragma unroll
    for (int ks = 0; ks < KS; ++ks)
      a[af][ks] = *(const short8v*)&As[(wr * 64 + af * 16 + lr) * DS + ks * 32 + lg * 8];

  f32x4 acc[4][2];
#pragma unroll
  for (int af = 0; af < 4; ++af)
#pragma unroll
    for (int nf = 0; nf < 2; ++nf) acc[af][nf] = (f32x4){0.f, 0.f, 0.f, 0.f};

#pragma unroll
  for (int ks = 0; ks < KS; ++ks) {
#pragma unroll
    for (int nf = 0; nf < 2; ++nf) {
      short8v b = *(const short8v*)&Bs[(wc * 32 + nf * 16 + lr) * DS + ks * 32 + lg * 8];
#pragma unroll
      for (int af = 0; af < 4; ++af)
        acc[af][nf] = __builtin_amdgcn_mfma_f32_16x16x32_bf16(a[af][ks], b, acc[af][nf], 0, 0, 0);
    }
  }

#pragma unroll
  for (int af = 0; af < 4; ++af) {
    int rbase = n0 + wr * 64 + af * 16 + lg * 4;
#pragma unroll
    for (int nf = 0; nf < 2; ++nf) {
      int col = wc * 32 + nf * 16 + lr;
      float bias = Bias[col];
      if (y == 0) {
#pragma unroll
        for (int r = 0; r < 4; ++r) {
          int n = rbase + r;
          if (n < N) Qb[(size_t)n * 128 + col] = bf16r((acc[af][nf][r] + bias) * QSCALE);
        }
      } else if (y == 1) {
#pragma unroll
        for (int r = 0; r < 4; ++r) {
          int n = rbase + r;
          if (n < N) KV[(size_t)n * 384 + col] = fp8e(acc[af][nf][r] + bias);
        }
      } else if (y == 2) {
#pragma unroll
        for (int r = 0; r < 4; ++r) {
          int n = rbase + r;
          if (n < N)
            *(unsigned short*)&KV[(size_t)n * 384 + 128 + col * 2] =
                bf16r(acc[af][nf][r] + bias);
        }
      } else {
#pragma unroll
        for (int r = 0; r < 4; ++r) {
          int n = rbase + r;
          if (n < N) Os[(size_t)n * 128 + col] = acc[af][nf][r] + bias;
        }
      }
    }
  }
}

// ---------------- level D: fill_csr + layer-1 gemm, interleaved ----------------

template <int DIN>
__global__ __launch_bounds__(512) void fill_gemm1(
    const int* __restrict__ src, const int* __restrict__ dst,
    const int* __restrict__ rank, const int* __restrict__ rowptr,
    int* __restrict__ csr_src, int E, int epb4,
    const unsigned short* __restrict__ xb, int N,
    const unsigned short* __restrict__ Wt0, const float* __restrict__ B0,
    const unsigned short* __restrict__ Wt1, const float* __restrict__ B1,
    const unsigned short* __restrict__ Wt2, const float* __restrict__ B2,
    const unsigned short* __restrict__ Wt3, const float* __restrict__ B3,
    unsigned short* __restrict__ Qb, unsigned char* __restrict__ KV,
    float* __restrict__ Os) {
  int b = blockIdx.x;
  int b5 = b / 5, r5 = b - b5 * 5;
  if (r5 == 0) {
    int e4 = E >> 2;
    int end = min((b5 + 1) * epb4, e4);
    for (int i = b5 * epb4 + threadIdx.x; i < end; i += 512) {
      int4 d4 = ((const int4*)dst)[i];
      int4 r4 = ((const int4*)rank)[i];
      int4 s4 = ((const int4*)src)[i];
      csr_src[rowptr[d4.x] + r4.x] = s4.x;
      csr_src[rowptr[d4.y] + r4.y] = s4.y;
      csr_src[rowptr[d4.z] + r4.z] = s4.z;
      csr_src[rowptr[d4.w] + r4.w] = s4.w;
    }
    if (b5 == 0 && threadIdx.x == 0) {
      for (int e = E & ~3; e < E; ++e) csr_src[rowptr[dst[e]] + rank[e]] = src[e];
    }
    return;
  }
  int g = b5 * 4 + r5 - 1;
  gemm4_tile<DIN>(g >> 2, g & 3, threadIdx.x, xb, N, Wt0, B0, Wt1, B1,
                  Wt2, B2, Wt3, B3, Qb, KV, Os);
}

template <int DIN>
__global__ __launch_bounds__(512) void gemm4(
    const unsigned short* __restrict__ xb, int N,
    const unsigned short* __restrict__ Wt0, const float* __restrict__ B0,
    const unsigned short* __restrict__ Wt1, const float* __restrict__ B1,
    const unsigned short* __restrict__ Wt2, const float* __restrict__ B2,
    const unsigned short* __restrict__ Wt3, const float* __restrict__ B3,
    unsigned short* __restrict__ Qb, unsigned char* __restrict__ KV,
    float* __restrict__ Os) {
  gemm4_tile<DIN>(blockIdx.x, blockIdx.y, threadIdx.x, xb, N, Wt0, B0, Wt1, B1,
                  Wt2, B2, Wt3, B3, Qb, KV, Os);
}

// ---------------- edge aggregation: 4 x 16-lane streams ----------------
// Wave = 1 node. Stream g4 = lane>>4 handles edges e = beg+g4+4*it; sublane
// sl = lane&15 owns dims [8*sl, 8*sl+8). Dot reduce = 4 shfl levels.
// Deferred-max (slack 8); 2 merge rounds (^16, ^32); m init -1e30 (NaN-safe).
// kv row: k fp8 [0,128), v bf16 [128,384). q bf16 pre-scaled.

template <bool RELU>
__global__ __launch_bounds__(256) void edge_agg4(
    const unsigned short* __restrict__ qb, const unsigned char* __restrict__ kv,
    const int* __restrict__ rowptr, const int* __restrict__ csr_src,
    const float* skip, unsigned short* __restrict__ outp, int N) {
  int tid = threadIdx.x;
  int lane = tid & 63;
  int wv = tid >> 6;
  int n = blockIdx.x * 4 + wv;
  if (n >= N) return;
  int g4 = lane >> 4;
  int sl = lane & 15;
  uint4 qp = *(const uint4*)&qb[(size_t)n * 128 + 8 * sl];
  float q0 = bf16f((unsigned short)(qp.x & 0xffff)), q1 = bf16f((unsigned short)(qp.x >> 16));
  float q2 = bf16f((unsigned short)(qp.y & 0xffff)), q3 = bf16f((unsigned short)(qp.y >> 16));
  float q4 = bf16f((unsigned short)(qp.z & 0xffff)), q5 = bf16f((unsigned short)(qp.z >> 16));
  float q6 = bf16f((unsigned short)(qp.w & 0xffff)), q7 = bf16f((unsigned short)(qp.w >> 16));
  int beg = rowptr[n];
  int deg = rowptr[n + 1] - beg;
  float m = -1e30f, lsum = 0.f;
  float acc[8];
#pragma unroll
  for (int j = 0; j < 8; ++j) acc[j] = 0.f;
  int cnt = (deg - g4 + 3) >> 2;
  if (cnt < 0) cnt = 0;
  const int* cp = csr_src + beg + g4;
  unsigned ko = 8u * sl, vo = 128u + 16u * sl;
  uint2 k0 = {0, 0}, k1 = {0, 0};
  uint4 v0 = {0, 0, 0, 0}, v1 = {0, 0, 0, 0};
  if (cnt >= 1) {
    unsigned r = (unsigned)cp[0] * 384u;
    k0 = *(const uint2*)(kv + r + ko);
    v0 = *(const uint4*)(kv + r + vo);
  }
  if (cnt >= 2) {
    unsigned r = (unsigned)cp[4] * 384u;
    k1 = *(const uint2*)(kv + r + ko);
    v1 = *(const uint4*)(kv + r + vo);
  }
  for (int it = 0; it < cnt; ++it) {
    uint2 kc = k0;
    uint4 vc = v0;
    k0 = k1;
    v0 = v1;
    if (it + 2 < cnt) {
      unsigned r = (unsigned)cp[4 * (it + 2)] * 384u;
      k1 = *(const uint2*)(kv + r + ko);
      v1 = *(const uint4*)(kv + r + vo);
    }
#ifdef HW_FP8_DEC
    f32x2 p01 = __builtin_amdgcn_cvt_pk_f32_fp8((int)kc.x, false);
    f32x2 p23 = __builtin_amdgcn_cvt_pk_f32_fp8((int)kc.x, true);
    f32x2 p45 = __builtin_amdgcn_cvt_pk_f32_fp8((int)kc.y, false);
    f32x2 p67 = __builtin_amdgcn_cvt_pk_f32_fp8((int)kc.y, true);
    float d = q0 * p01[0] + q1 * p01[1] + q2 * p23[0] + q3 * p23[1] +
              q4 * p45[0] + q5 * p45[1] + q6 * p67[0] + q7 * p67[1];
#else
    float d = q0 * fp8f_sw(kc.x & 0xffu) + q1 * fp8f_sw((kc.x >> 8) & 0xffu) +
              q2 * fp8f_sw((kc.x >> 16) & 0xffu) + q3 * fp8f_sw(kc.x >> 24) +
              q4 * fp8f_sw(kc.y & 0xffu) + q5 * fp8f_sw((kc.y >> 8) & 0xffu) +
              q6 * fp8f_sw((kc.y >> 16) & 0xffu) + q7 * fp8f_sw(kc.y >> 24);
#endif
#pragma unroll
    for (int off = 1; off < 16; off <<= 1) d += __shfl_xor(d, off);
    float w0 = bf16f((unsigned short)(vc.x & 0xffff)), w1 = bf16f((unsigned short)(vc.x >> 16));
    float w2 = bf16f((unsigned short)(vc.y & 0xffff)), w3 = bf16f((unsigned short)(vc.y >> 16));
    float w4 = bf16f((unsigned short)(vc.z & 0xffff)), w5 = bf16f((unsigned short)(vc.z >> 16));
    float w6 = bf16f((unsigned short)(vc.w & 0xffff)), w7 = bf16f((unsigned short)(vc.w >> 16));
    if (d > m + 8.f) {        // rare: new max beyond slack -> rescale
      float cf = __expf(m - d);
      lsum = lsum * cf + 1.f;
      acc[0] = acc[0] * cf + w0; acc[1] = acc[1] * cf + w1;
      acc[2] = acc[2] * cf + w2; acc[3] = acc[3] * cf + w3;
      acc[4] = acc[4] * cf + w4; acc[5] = acc[5] * cf + w5;
      acc[6] = acc[6] * cf + w6; acc[7] = acc[7] * cf + w7;
      m = d;
    } else {                  // common: accumulate against stale max
      float ef = __expf(d - m);
      lsum += ef;
      acc[0] += ef * w0; acc[1] += ef * w1;
      acc[2] += ef * w2; acc[3] += ef * w3;
      acc[4] += ef * w4; acc[5] += ef * w5;
      acc[6] += ef * w6; acc[7] += ef * w7;
    }
  }
  // merge 4 stream states: ^16 then ^32 (m=-1e30 keeps empty streams NaN-free)
#pragma unroll
  for (int ofs = 16; ofs <= 32; ofs <<= 1) {
    float mo = __shfl_xor(m, ofs);
    float lo = __shfl_xor(lsum, ofs);
    float ao[8];
#pragma unroll
    for (int j = 0; j < 8; ++j) ao[j] = __shfl_xor(acc[j], ofs);
    float M = fmaxf(m, mo);
    float c1 = __expf(m - M);
    float c2 = __expf(mo - M);
    lsum = lsum * c1 + lo * c2;
#pragma unroll
    for (int j = 0; j < 8; ++j) acc[j] = acc[j] * c1 + ao[j] * c2;
    m = M;
  }
  if (lane < 16) {
    float rl = (deg > 0) ? 1.f / (lsum + 1e-16f) : 0.f;
    const float* sp = skip + (size_t)n * 128 + 8 * sl;
    float4 s0 = ((const float4*)sp)[0];
    float4 s1 = ((const float4*)sp)[1];
    float o0 = s0.x + acc[0] * rl, o1 = s0.y + acc[1] * rl;
    float o2 = s0.z + acc[2] * rl, o3 = s0.w + acc[3] * rl;
    float o4 = s1.x + acc[4] * rl, o5 = s1.y + acc[5] * rl;
    float o6 = s1.z + acc[6] * rl, o7 = s1.w + acc[7] * rl;
    if (RELU) {
      o0 = fmaxf(o0, 0.f); o1 = fmaxf(o1, 0.f); o2 = fmaxf(o2, 0.f); o3 = fmaxf(o3, 0.f);
      o4 = fmaxf(o4, 0.f); o5 = fmaxf(o5, 0.f); o6 = fmaxf(o6, 0.f); o7 = fmaxf(o7, 0.f);
    }
    uint4 pk;
    pk.x = pack_bf16_2(o0, o1);
    pk.y = pack_bf16_2(o2, o3);
    pk.z = pack_bf16_2(o4, o5);
    pk.w = pack_bf16_2(o6, o7);
    *(uint4*)&outp[(size_t)n * 128 + 8 * sl] = pk;
  }
}

// ---------------- global mean pool (batch sorted, bf16 input) ----------------

__global__ __launch_bounds__(128) void pool_kernel(const unsigned short* __restrict__ h,
                                                   const int* __restrict__ batch,
                                                   float* __restrict__ out, int N) {
  int g = blockIdx.x;
  int lo = 0, hi = N;
  while (lo < hi) { int mid = (lo + hi) >> 1; if (batch[mid] < g) lo = mid + 1; else hi = mid; }
  int s0 = lo;
  hi = N;
  while (lo < hi) { int mid = (lo + hi) >> 1; if (batch[mid] <= g) lo = mid + 1; else hi = mid; }
  int s1 = lo;
  int j = threadIdx.x;
  float acc = 0.f;
  for (int n = s0; n < s1; ++n) acc += bf16f(h[(size_t)n * 128 + j]);
  out[(size_t)g * 128 + j] = acc / fmaxf((float)(s1 - s0), 1.f);
}

// ---------------- launch ----------------

extern "C" void kernel_launch(void* const* d_in, const int* in_sizes, int n_in,
                              void* d_out, int out_size, void* d_ws, size_t ws_size,
                              hipStream_t stream) {
  const float* x = (const float*)d_in[0];
  const int* ei = (const int*)d_in[1];
  const int* batch = (const int*)d_in[2];
  const float* Wq1 = (const float*)d_in[3];
  const float* bq1 = (const float*)d_in[4];
  const float* Wk1 = (const float*)d_in[5];
  const float* bk1 = (const float*)d_in[6];
  const float* Wv1 = (const float*)d_in[7];
  const float* bv1 = (const float*)d_in[8];
  const float* Ws1 = (const float*)d_in[9];
  const float* bs1 = (const float*)d_in[10];
  const float* Wq2 = (const float*)d_in[11];
  const float* bq2 = (const float*)d_in[12];
  const float* Wk2 = (const float*)d_in[13];
  const float* bk2 = (const float*)d_in[14];
  const float* Wv2 = (const float*)d_in[15];
  const float* bv2 = (const float*)d_in[16];
  const float* Ws2 = (const float*)d_in[17];
  const float* bs2 = (const float*)d_in[18];

  int N = in_sizes[0] / D1;  // 50000
  int E = in_sizes[1] / 2;   // 800000
  int NG = out_size / DH;    // 512
  const int* src = ei;
  const int* dst = ei + E;

  char* ws = (char*)d_ws;
  unsigned short* qb = (unsigned short*)ws;  ws += (size_t)N * DH * 2;   // bf16 q (pre-scaled)
  unsigned char* kvb = (unsigned char*)ws;   ws += (size_t)N * 384;     // k fp8 | v bf16
  ws = (char*)(((size_t)ws + 255) & ~(size_t)255);
  float* s = (float*)ws;             ws += (size_t)N * DH * 4;   // skip
  unsigned short* h1b = (unsigned short*)ws; ws += (size_t)N * DH * 2;  // bf16 h1 / h2
  unsigned short* xb = (unsigned short*)ws;  ws += (size_t)N * D1 * 2;  // bf16 x
  unsigned short* wt[8];
  for (int m = 0; m < 8; ++m) {
    int din = (m < 4) ? 64 : 128;
    wt[m] = (unsigned short*)ws;
    ws += (size_t)128 * din * 2;
  }
  ws = (char*)(((size_t)ws + 255) & ~(size_t)255);
  int* rowptr = (int*)ws; ws += (size_t)(N + 1) * 4;
  ws = (char*)(((size_t)ws + 255) & ~(size_t)255);
  int* deg = (int*)ws;  ws += (size_t)N * 4;
  int* incl = (int*)ws; ws += (size_t)N * 4;
  int* sums = (int*)ws; ws += 1024;
  int* rank = (int*)ws; ws += (size_t)E * 4;
  int* csr = (int*)ws;  ws += (size_t)E * 4;

  int nch = (N + SCHUNK - 1) / SCHUNK;
  int nbHist = ((E >> 2) + 255) / 256;
  int nb = (N + 127) / 128;           // gemm tiles (x4 y)
  int epb4 = ((E >> 2) + nb - 1) / nb;  // int4 edges per fill block

  hipMemsetAsync(deg, 0, (size_t)N * 4, stream);

  // level A: histogram+ranks + weight/x prep (one dispatch)
  hist_prep<<<nbHist + 768, 256, 0, stream>>>(
      dst, deg, rank, E, nbHist, Wq1, Wk1, Wv1, Ws1, Wq2, Wk2, Wv2, Ws2,
      wt[0], wt[1], wt[2], wt[3], wt[4], wt[5], wt[6], wt[7],
      (const float4*)x, (uint2*)xb, N * D1 / 4);
  scan_chunks<<<nch, 256, 0, stream>>>(deg, incl, sums, N);
  finalize_rowptr<<<(N + 255) / 256, 256, 0, stream>>>(incl, sums, rowptr, N);
  // level D: CSR fill + layer-1 gemm, block-interleaved 1:4
  fill_gemm1<D1><<<nb * 5, 512, 0, stream>>>(
      src, dst, rank, rowptr, csr, E, epb4, xb, N,
      wt[0], bq1, wt[1], bk1, wt[2], bv1, wt[3], bs1, qb, kvb, s);
  edge_agg4<true><<<(N + 3) / 4, 256, 0, stream>>>(
      qb, kvb, rowptr, csr, s, h1b, N);
  // layer 2
  gemm4<DH><<<dim3(nb, 4), 512, 0, stream>>>(h1b, N, wt[4], bq2, wt[5], bk2,
                                             wt[6], bv2, wt[7], bs2, qb, kvb, s);
  edge_agg4<false><<<(N + 3) / 4, 256, 0, stream>>>(
      qb, kvb, rowptr, csr, s, h1b, N);
  // mean pool (bf16 input)
  pool_kernel<<<NG, 128, 0, stream>>>(h1b, batch, (float*)d_out, N);
}

// Round 14
// 239.278 us; speedup vs baseline: 1.5796x; 1.0806x over previous
//
#include <hip/hip_runtime.h>
#include <hip/hip_fp8.h>
#include <math.h>

// DrugEncoder: 2x TransformerConv (heads=1) + global mean pool.
// N=50000 nodes, E=800000 edges, G=512 graphs, D_IN=64, D_HID=D_EMB=128.
//
// R14: kv row -> 256B, both k AND v in fp8 e4m3 (halves of the row, disjoint
//      64B lines for gemm y=1/y=2 writers). Edge gather 384->256 B/edge.
//      Rest unchanged from R13 (4x16-lane edge streams, HW fp8 decode,
//      atomic-free fill + interleaved gemm1, bf16 h1/h2 + bf16 pool).

constexpr int D1 = 64;
constexpr int DH = 128;
constexpr int SCHUNK = 1024;
constexpr float QSCALE = 0.08838834764831845f;  // 1/sqrt(128)

typedef __attribute__((ext_vector_type(8))) short short8v;
typedef __attribute__((ext_vector_type(4))) float f32x4;
typedef __attribute__((ext_vector_type(2))) float f32x2;

#if __has_builtin(__builtin_amdgcn_cvt_pk_f32_fp8)
#define HW_FP8_DEC 1
#endif

__device__ inline unsigned short bf16r(float f) {
  unsigned u = __float_as_uint(f);
  return (unsigned short)((u + 0x7fffu + ((u >> 16) & 1u)) >> 16);
}

__device__ inline unsigned pack_bf16_2(float a, float b) {
  return (unsigned)bf16r(a) | ((unsigned)bf16r(b) << 16);
}

__device__ inline float bf16f(unsigned short u) {
  return __uint_as_float(((unsigned)u) << 16);
}

__device__ inline unsigned char fp8e(float f) {
  __hip_fp8_e4m3 h(f);
  return h.__x;
}

#ifndef HW_FP8_DEC
__device__ inline float fp8f_sw(unsigned b) {
  unsigned e = (b >> 3) & 15u, mm = b & 7u;
  float v;
  if (e == 0) v = (float)mm * 0.001953125f;  // m * 2^-9
  else v = __uint_as_float(((e + 119u) << 23) | (mm << 20));
  return (b & 0x80u) ? -v : v;
}
#endif

// decode 8 fp8 (two dwords) into w[0..8)
__device__ inline void fp8_dec8(unsigned lo, unsigned hi, float* w) {
#ifdef HW_FP8_DEC
  f32x2 p01 = __builtin_amdgcn_cvt_pk_f32_fp8((int)lo, false);
  f32x2 p23 = __builtin_amdgcn_cvt_pk_f32_fp8((int)lo, true);
  f32x2 p45 = __builtin_amdgcn_cvt_pk_f32_fp8((int)hi, false);
  f32x2 p67 = __builtin_amdgcn_cvt_pk_f32_fp8((int)hi, true);
  w[0] = p01[0]; w[1] = p01[1]; w[2] = p23[0]; w[3] = p23[1];
  w[4] = p45[0]; w[5] = p45[1]; w[6] = p67[0]; w[7] = p67[1];
#else
  w[0] = fp8f_sw(lo & 0xffu); w[1] = fp8f_sw((lo >> 8) & 0xffu);
  w[2] = fp8f_sw((lo >> 16) & 0xffu); w[3] = fp8f_sw(lo >> 24);
  w[4] = fp8f_sw(hi & 0xffu); w[5] = fp8f_sw((hi >> 8) & 0xffu);
  w[6] = fp8f_sw((hi >> 16) & 0xffu); w[7] = fp8f_sw(hi >> 24);
#endif
}

// ---------------- level A: histogram(+ranks) + weight/x prep ----------------

__global__ __launch_bounds__(256) void hist_prep(
    const int* __restrict__ dst, int* __restrict__ deg, int* __restrict__ rank,
    int E, int nbHist,
    const float* w0, const float* w1, const float* w2, const float* w3,
    const float* w4, const float* w5, const float* w6, const float* w7,
    unsigned short* t0, unsigned short* t1, unsigned short* t2,
    unsigned short* t3, unsigned short* t4, unsigned short* t5,
    unsigned short* t6, unsigned short* t7,
    const float4* __restrict__ x, uint2* __restrict__ xb, int n4) {
  int b = blockIdx.x;
  int tid = threadIdx.x;
  if (b < nbHist) {
    int i = b * 256 + tid;
    if (i < (E >> 2)) {
      int4 d4 = ((const int4*)dst)[i];
      int4 r4;
      r4.x = atomicAdd(&deg[d4.x], 1);
      r4.y = atomicAdd(&deg[d4.y], 1);
      r4.z = atomicAdd(&deg[d4.z], 1);
      r4.w = atomicAdd(&deg[d4.w], 1);
      ((int4*)rank)[i] = r4;
    }
    if (b == 0 && tid == 0) {
      for (int e = E & ~3; e < E; ++e) rank[e] = atomicAdd(&deg[dst[e]], 1);
    }
    return;
  }
  int g = b - nbHist;
  if (g < 512) {
    int m = g >> 6, bx = g & 63;
    const float* W;
    unsigned short* T;
    switch (m) {
      case 0: W = w0; T = t0; break;
      case 1: W = w1; T = t1; break;
      case 2: W = w2; T = t2; break;
      case 3: W = w3; T = t3; break;
      case 4: W = w4; T = t4; break;
      case 5: W = w5; T = t5; break;
      case 6: W = w6; T = t6; break;
      default: W = w7; T = t7; break;
    }
    int din = (m < 4) ? 64 : 128;
    int total = din * 128;
    int i = bx * 256 + tid;
    if (i < total) {
      int r = i >> 7, c = i & 127;  // W[r][c]
      T[c * din + r] = bf16r(W[i]);
    }
    return;
  }
  int bx = g - 512;  // 256 blocks
  for (int i = bx * 256 + tid; i < n4; i += 256 * 256) {
    float4 v = x[i];
    uint2 o;
    o.x = pack_bf16_2(v.x, v.y);
    o.y = pack_bf16_2(v.z, v.w);
    xb[i] = o;
  }
}

// ---------------- CSR scan ----------------

__global__ void scan_chunks(const int* __restrict__ deg, int* __restrict__ incl,
                            int* __restrict__ sums, int N) {
  __shared__ int lds[256];
  int b = blockIdx.x, tid = threadIdx.x;
  int base = b * SCHUNK + tid * 4;
  int e0 = (base + 0 < N) ? deg[base + 0] : 0;
  int e1 = (base + 1 < N) ? deg[base + 1] : 0;
  int e2 = (base + 2 < N) ? deg[base + 2] : 0;
  int e3 = (base + 3 < N) ? deg[base + 3] : 0;
  int t0 = e0, t1 = t0 + e1, t2 = t1 + e2, t3 = t2 + e3;
  lds[tid] = t3;
  __syncthreads();
  for (int off = 1; off < 256; off <<= 1) {
    int v = (tid >= off) ? lds[tid - off] : 0;
    __syncthreads();
    lds[tid] += v;
    __syncthreads();
  }
  int excl = (tid > 0) ? lds[tid - 1] : 0;
  if (base + 0 < N) incl[base + 0] = t0 + excl;
  if (base + 1 < N) incl[base + 1] = t1 + excl;
  if (base + 2 < N) incl[base + 2] = t2 + excl;
  if (base + 3 < N) incl[base + 3] = t3 + excl;
  if (tid == 255) sums[b] = lds[255];
}

__global__ void finalize_rowptr(const int* __restrict__ incl, const int* __restrict__ sums,
                                int* __restrict__ rowptr, int N) {
  int n = blockIdx.x * blockDim.x + threadIdx.x;
  if (n < N) {
    int ch = n / SCHUNK;
    int off = 0;
    for (int i = 0; i < ch; ++i) off += sums[i];
    rowptr[n + 1] = incl[n] + off;
  }
  if (n == 0) rowptr[0] = 0;
}

// ---------------- bf16 MFMA 4-way linear (tile body) ----------------
// y: 0=q(bf16 pre-scaled) 1=k(fp8 -> kv[0..128)) 2=v(fp8 -> kv[128..256))
// 3=skip(fp32). 512 threads = 8 waves, 2x4: wave owns 64 rows x 32 cols.

template <int DIN>
__device__ __forceinline__ void gemm4_tile(
    int bx, int y, int tid,
    const unsigned short* __restrict__ xb, int N,
    const unsigned short* __restrict__ Wt0, const float* __restrict__ B0,
    const unsigned short* __restrict__ Wt1, const float* __restrict__ B1,
    const unsigned short* __restrict__ Wt2, const float* __restrict__ B2,
    const unsigned short* __restrict__ Wt3, const float* __restrict__ B3,
    unsigned short* __restrict__ Qb, unsigned char* __restrict__ KV,
    float* __restrict__ Os) {
  constexpr int DS = DIN + 8;
  __shared__ __align__(16) unsigned short As[128 * DS];
  __shared__ __align__(16) unsigned short Bs[128 * DS];
  const unsigned short* Wt;
  const float* Bias;
  switch (y) {
    case 0: Wt = Wt0; Bias = B0; break;
    case 1: Wt = Wt1; Bias = B1; break;
    case 2: Wt = Wt2; Bias = B2; break;
    default: Wt = Wt3; Bias = B3; break;
  }
  int n0 = bx * 128;

  constexpr int CPR = DIN / 8;
  constexpr int ACH = 128 * CPR;
#pragma unroll
  for (int c = tid; c < ACH; c += 512) {
    int row = c / CPR, c8 = c - row * CPR;
    int n = n0 + row;
    uint4 val = {0u, 0u, 0u, 0u};
    if (n < N) val = *(const uint4*)&xb[(size_t)n * DIN + c8 * 8];
    *(uint4*)&As[row * DS + c8 * 8] = val;
  }
#pragma unroll
  for (int c = tid; c < ACH; c += 512) {
    int row = c / CPR, c8 = c - row * CPR;
    uint4 val = *(const uint4*)&Wt[(size_t)row * DIN + c8 * 8];
    *(uint4*)&Bs[row * DS + c8 * 8] = val;
  }
  __syncthreads();

  int w = tid >> 6, lane = tid & 63, lr = lane & 15, lg = lane >> 4;
  int wr = w >> 2;
  int wc = w & 3;
  constexpr int KS = DIN / 32;

  short8v a[4][KS];
#pragma unroll
  for (int af = 0; af < 4; ++af)
#pragma unroll
    for (int ks = 0; ks < KS; ++ks)
      a[af][ks] = *(const short8v*)&As[(wr * 64 + af * 16 + lr) * DS + ks * 32 + lg * 8];

  f32x4 acc[4][2];
#pragma unroll
  for (int af = 0; af < 4; ++af)
#pragma unroll
    for (int nf = 0; nf < 2; ++nf) acc[af][nf] = (f32x4){0.f, 0.f, 0.f, 0.f};

#pragma unroll
  for (int ks = 0; ks < KS; ++ks) {
#pragma unroll
    for (int nf = 0; nf < 2; ++nf) {
      short8v b = *(const short8v*)&Bs[(wc * 32 + nf * 16 + lr) * DS + ks * 32 + lg * 8];
#pragma unroll
      for (int af = 0; af < 4; ++af)
        acc[af][nf] = __builtin_amdgcn_mfma_f32_16x16x32_bf16(a[af][ks], b, acc[af][nf], 0, 0, 0);
    }
  }

#pragma unroll
  for (int af = 0; af < 4; ++af) {
    int rbase = n0 + wr * 64 + af * 16 + lg * 4;
#pragma unroll
    for (int nf = 0; nf < 2; ++nf) {
      int col = wc * 32 + nf * 16 + lr;
      float bias = Bias[col];
      if (y == 0) {
#pragma unroll
        for (int r = 0; r < 4; ++r) {
          int n = rbase + r;
          if (n < N) Qb[(size_t)n * 128 + col] = bf16r((acc[af][nf][r] + bias) * QSCALE);
        }
      } else if (y == 1) {
#pragma unroll
        for (int r = 0; r < 4; ++r) {
          int n = rbase + r;
          if (n < N) KV[(size_t)n * 256 + col] = fp8e(acc[af][nf][r] + bias);
        }
      } else if (y == 2) {
#pragma unroll
        for (int r = 0; r < 4; ++r) {
          int n = rbase + r;
          if (n < N) KV[(size_t)n * 256 + 128 + col] = fp8e(acc[af][nf][r] + bias);
        }
      } else {
#pragma unroll
        for (int r = 0; r < 4; ++r) {
          int n = rbase + r;
          if (n < N) Os[(size_t)n * 128 + col] = acc[af][nf][r] + bias;
        }
      }
    }
  }
}

// ---------------- level D: fill_csr + layer-1 gemm, interleaved ----------------

template <int DIN>
__global__ __launch_bounds__(512) void fill_gemm1(
    const int* __restrict__ src, const int* __restrict__ dst,
    const int* __restrict__ rank, const int* __restrict__ rowptr,
    int* __restrict__ csr_src, int E, int epb4,
    const unsigned short* __restrict__ xb, int N,
    const unsigned short* __restrict__ Wt0, const float* __restrict__ B0,
    const unsigned short* __restrict__ Wt1, const float* __restrict__ B1,
    const unsigned short* __restrict__ Wt2, const float* __restrict__ B2,
    const unsigned short* __restrict__ Wt3, const float* __restrict__ B3,
    unsigned short* __restrict__ Qb, unsigned char* __restrict__ KV,
    float* __restrict__ Os) {
  int b = blockIdx.x;
  int b5 = b / 5, r5 = b - b5 * 5;
  if (r5 == 0) {
    int e4 = E >> 2;
    int end = min((b5 + 1) * epb4, e4);
    for (int i = b5 * epb4 + threadIdx.x; i < end; i += 512) {
      int4 d4 = ((const int4*)dst)[i];
      int4 r4 = ((const int4*)rank)[i];
      int4 s4 = ((const int4*)src)[i];
      csr_src[rowptr[d4.x] + r4.x] = s4.x;
      csr_src[rowptr[d4.y] + r4.y] = s4.y;
      csr_src[rowptr[d4.z] + r4.z] = s4.z;
      csr_src[rowptr[d4.w] + r4.w] = s4.w;
    }
    if (b5 == 0 && threadIdx.x == 0) {
      for (int e = E & ~3; e < E; ++e) csr_src[rowptr[dst[e]] + rank[e]] = src[e];
    }
    return;
  }
  int g = b5 * 4 + r5 - 1;
  gemm4_tile<DIN>(g >> 2, g & 3, threadIdx.x, xb, N, Wt0, B0, Wt1, B1,
                  Wt2, B2, Wt3, B3, Qb, KV, Os);
}

template <int DIN>
__global__ __launch_bounds__(512) void gemm4(
    const unsigned short* __restrict__ xb, int N,
    const unsigned short* __restrict__ Wt0, const float* __restrict__ B0,
    const unsigned short* __restrict__ Wt1, const float* __restrict__ B1,
    const unsigned short* __restrict__ Wt2, const float* __restrict__ B2,
    const unsigned short* __restrict__ Wt3, const float* __restrict__ B3,
    unsigned short* __restrict__ Qb, unsigned char* __restrict__ KV,
    float* __restrict__ Os) {
  gemm4_tile<DIN>(blockIdx.x, blockIdx.y, threadIdx.x, xb, N, Wt0, B0, Wt1, B1,
                  Wt2, B2, Wt3, B3, Qb, KV, Os);
}

// ---------------- edge aggregation: 4 x 16-lane streams ----------------
// Wave = 1 node. Stream g4 = lane>>4 handles edges e = beg+g4+4*it; sublane
// sl = lane&15 owns dims [8*sl, 8*sl+8). Dot reduce = 4 shfl levels.
// Deferred-max (slack 8); merges ^16, ^32; m init -1e30 (NaN-safe).
// kv row 256B: k fp8 [0,128), v fp8 [128,256). q bf16 pre-scaled.

template <bool RELU>
__global__ __launch_bounds__(256) void edge_agg4(
    const unsigned short* __restrict__ qb, const unsigned char* __restrict__ kv,
    const int* __restrict__ rowptr, const int* __restrict__ csr_src,
    const float* skip, unsigned short* __restrict__ outp, int N) {
  int tid = threadIdx.x;
  int lane = tid & 63;
  int wv = tid >> 6;
  int n = blockIdx.x * 4 + wv;
  if (n >= N) return;
  int g4 = lane >> 4;
  int sl = lane & 15;
  uint4 qp = *(const uint4*)&qb[(size_t)n * 128 + 8 * sl];
  float q0 = bf16f((unsigned short)(qp.x & 0xffff)), q1 = bf16f((unsigned short)(qp.x >> 16));
  float q2 = bf16f((unsigned short)(qp.y & 0xffff)), q3 = bf16f((unsigned short)(qp.y >> 16));
  float q4 = bf16f((unsigned short)(qp.z & 0xffff)), q5 = bf16f((unsigned short)(qp.z >> 16));
  float q6 = bf16f((unsigned short)(qp.w & 0xffff)), q7 = bf16f((unsigned short)(qp.w >> 16));
  int beg = rowptr[n];
  int deg = rowptr[n + 1] - beg;
  float m = -1e30f, lsum = 0.f;
  float acc[8];
#pragma unroll
  for (int j = 0; j < 8; ++j) acc[j] = 0.f;
  int cnt = (deg - g4 + 3) >> 2;
  if (cnt < 0) cnt = 0;
  const int* cp = csr_src + beg + g4;
  unsigned ko = 8u * sl, vo = 128u + 8u * sl;
  uint2 k0 = {0, 0}, k1 = {0, 0};
  uint2 v0 = {0, 0}, v1 = {0, 0};
  if (cnt >= 1) {
    unsigned r = (unsigned)cp[0] * 256u;
    k0 = *(const uint2*)(kv + r + ko);
    v0 = *(const uint2*)(kv + r + vo);
  }
  if (cnt >= 2) {
    unsigned r = (unsigned)cp[4] * 256u;
    k1 = *(const uint2*)(kv + r + ko);
    v1 = *(const uint2*)(kv + r + vo);
  }
  for (int it = 0; it < cnt; ++it) {
    uint2 kc = k0;
    uint2 vc = v0;
    k0 = k1;
    v0 = v1;
    if (it + 2 < cnt) {
      unsigned r = (unsigned)cp[4 * (it + 2)] * 256u;
      k1 = *(const uint2*)(kv + r + ko);
      v1 = *(const uint2*)(kv + r + vo);
    }
    float kd[8];
    fp8_dec8(kc.x, kc.y, kd);
    float d = q0 * kd[0] + q1 * kd[1] + q2 * kd[2] + q3 * kd[3] +
              q4 * kd[4] + q5 * kd[5] + q6 * kd[6] + q7 * kd[7];
#pragma unroll
    for (int off = 1; off < 16; off <<= 1) d += __shfl_xor(d, off);
    float w[8];
    fp8_dec8(vc.x, vc.y, w);
    if (d > m + 8.f) {        // rare: new max beyond slack -> rescale
      float cf = __expf(m - d);
      lsum = lsum * cf + 1.f;
#pragma unroll
      for (int j = 0; j < 8; ++j) acc[j] = acc[j] * cf + w[j];
      m = d;
    } else {                  // common: accumulate against stale max
      float ef = __expf(d - m);
      lsum += ef;
#pragma unroll
      for (int j = 0; j < 8; ++j) acc[j] += ef * w[j];
    }
  }
  // merge 4 stream states: ^16 then ^32 (m=-1e30 keeps empty streams NaN-free)
#pragma unroll
  for (int ofs = 16; ofs <= 32; ofs <<= 1) {
    float mo = __shfl_xor(m, ofs);
    float lo = __shfl_xor(lsum, ofs);
    float ao[8];
#pragma unroll
    for (int j = 0; j < 8; ++j) ao[j] = __shfl_xor(acc[j], ofs);
    float M = fmaxf(m, mo);
    float c1 = __expf(m - M);
    float c2 = __expf(mo - M);
    lsum = lsum * c1 + lo * c2;
#pragma unroll
    for (int j = 0; j < 8; ++j) acc[j] = acc[j] * c1 + ao[j] * c2;
    m = M;
  }
  if (lane < 16) {
    float rl = (deg > 0) ? 1.f / (lsum + 1e-16f) : 0.f;
    const float* sp = skip + (size_t)n * 128 + 8 * sl;
    float4 s0 = ((const float4*)sp)[0];
    float4 s1 = ((const float4*)sp)[1];
    float o0 = s0.x + acc[0] * rl, o1 = s0.y + acc[1] * rl;
    float o2 = s0.z + acc[2] * rl, o3 = s0.w + acc[3] * rl;
    float o4 = s1.x + acc[4] * rl, o5 = s1.y + acc[5] * rl;
    float o6 = s1.z + acc[6] * rl, o7 = s1.w + acc[7] * rl;
    if (RELU) {
      o0 = fmaxf(o0, 0.f); o1 = fmaxf(o1, 0.f); o2 = fmaxf(o2, 0.f); o3 = fmaxf(o3, 0.f);
      o4 = fmaxf(o4, 0.f); o5 = fmaxf(o5, 0.f); o6 = fmaxf(o6, 0.f); o7 = fmaxf(o7, 0.f);
    }
    uint4 pk;
    pk.x = pack_bf16_2(o0, o1);
    pk.y = pack_bf16_2(o2, o3);
    pk.z = pack_bf16_2(o4, o5);
    pk.w = pack_bf16_2(o6, o7);
    *(uint4*)&outp[(size_t)n * 128 + 8 * sl] = pk;
  }
}

// ---------------- global mean pool (batch sorted, bf16 input) ----------------

__global__ __launch_bounds__(128) void pool_kernel(const unsigned short* __restrict__ h,
                                                   const int* __restrict__ batch,
                                                   float* __restrict__ out, int N) {
  int g = blockIdx.x;
  int lo = 0, hi = N;
  while (lo < hi) { int mid = (lo + hi) >> 1; if (batch[mid] < g) lo = mid + 1; else hi = mid; }
  int s0 = lo;
  hi = N;
  while (lo < hi) { int mid = (lo + hi) >> 1; if (batch[mid] <= g) lo = mid + 1; else hi = mid; }
  int s1 = lo;
  int j = threadIdx.x;
  float acc = 0.f;
  for (int n = s0; n < s1; ++n) acc += bf16f(h[(size_t)n * 128 + j]);
  out[(size_t)g * 128 + j] = acc / fmaxf((float)(s1 - s0), 1.f);
}

// ---------------- launch ----------------

extern "C" void kernel_launch(void* const* d_in, const int* in_sizes, int n_in,
                              void* d_out, int out_size, void* d_ws, size_t ws_size,
                              hipStream_t stream) {
  const float* x = (const float*)d_in[0];
  const int* ei = (const int*)d_in[1];
  const int* batch = (const int*)d_in[2];
  const float* Wq1 = (const float*)d_in[3];
  const float* bq1 = (const float*)d_in[4];
  const float* Wk1 = (const float*)d_in[5];
  const float* bk1 = (const float*)d_in[6];
  const float* Wv1 = (const float*)d_in[7];
  const float* bv1 = (const float*)d_in[8];
  const float* Ws1 = (const float*)d_in[9];
  const float* bs1 = (const float*)d_in[10];
  const float* Wq2 = (const float*)d_in[11];
  const float* bq2 = (const float*)d_in[12];
  const float* Wk2 = (const float*)d_in[13];
  const float* bk2 = (const float*)d_in[14];
  const float* Wv2 = (const float*)d_in[15];
  const float* bv2 = (const float*)d_in[16];
  const float* Ws2 = (const float*)d_in[17];
  const float* bs2 = (const float*)d_in[18];

  int N = in_sizes[0] / D1;  // 50000
  int E = in_sizes[1] / 2;   // 800000
  int NG = out_size / DH;    // 512
  const int* src = ei;
  const int* dst = ei + E;

  char* ws = (char*)d_ws;
  unsigned short* qb = (unsigned short*)ws;  ws += (size_t)N * DH * 2;   // bf16 q (pre-scaled)
  unsigned char* kvb = (unsigned char*)ws;   ws += (size_t)N * 256;     // k fp8 | v fp8
  ws = (char*)(((size_t)ws + 255) & ~(size_t)255);
  float* s = (float*)ws;             ws += (size_t)N * DH * 4;   // skip
  unsigned short* h1b = (unsigned short*)ws; ws += (size_t)N * DH * 2;  // bf16 h1 / h2
  unsigned short* xb = (unsigned short*)ws;  ws += (size_t)N * D1 * 2;  // bf16 x
  unsigned short* wt[8];
  for (int m = 0; m < 8; ++m) {
    int din = (m < 4) ? 64 : 128;
    wt[m] = (unsigned short*)ws;
    ws += (size_t)128 * din * 2;
  }
  ws = (char*)(((size_t)ws + 255) & ~(size_t)255);
  int* rowptr = (int*)ws; ws += (size_t)(N + 1) * 4;
  ws = (char*)(((size_t)ws + 255) & ~(size_t)255);
  int* deg = (int*)ws;  ws += (size_t)N * 4;
  int* incl = (int*)ws; ws += (size_t)N * 4;
  int* sums = (int*)ws; ws += 1024;
  int* rank = (int*)ws; ws += (size_t)E * 4;
  int* csr = (int*)ws;  ws += (size_t)E * 4;

  int nch = (N + SCHUNK - 1) / SCHUNK;
  int nbHist = ((E >> 2) + 255) / 256;
  int nb = (N + 127) / 128;           // gemm tiles (x4 y)
  int epb4 = ((E >> 2) + nb - 1) / nb;  // int4 edges per fill block

  hipMemsetAsync(deg, 0, (size_t)N * 4, stream);

  // level A: histogram+ranks + weight/x prep (one dispatch)
  hist_prep<<<nbHist + 768, 256, 0, stream>>>(
      dst, deg, rank, E, nbHist, Wq1, Wk1, Wv1, Ws1, Wq2, Wk2, Wv2, Ws2,
      wt[0], wt[1], wt[2], wt[3], wt[4], wt[5], wt[6], wt[7],
      (const float4*)x, (uint2*)xb, N * D1 / 4);
  scan_chunks<<<nch, 256, 0, stream>>>(deg, incl, sums, N);
  finalize_rowptr<<<(N + 255) / 256, 256, 0, stream>>>(incl, sums, rowptr, N);
  // level D: CSR fill + layer-1 gemm, block-interleaved 1:4
  fill_gemm1<D1><<<nb * 5, 512, 0, stream>>>(
      src, dst, rank, rowptr, csr, E, epb4, xb, N,
      wt[0], bq1, wt[1], bk1, wt[2], bv1, wt[3], bs1, qb, kvb, s);
  edge_agg4<true><<<(N + 3) / 4, 256, 0, stream>>>(
      qb, kvb, rowptr, csr, s, h1b, N);
  // layer 2
  gemm4<DH><<<dim3(nb, 4), 512, 0, stream>>>(h1b, N, wt[4], bq2, wt[5], bk2,
                                             wt[6], bv2, wt[7], bs2, qb, kvb, s);
  edge_agg4<false><<<(N + 3) / 4, 256, 0, stream>>>(
      qb, kvb, rowptr, csr, s, h1b, N);
  // mean pool (bf16 input)
  pool_kernel<<<NG, 128, 0, stream>>>(h1b, batch, (float*)d_out, N);
}